// Round 1
// baseline (1213.871 us; speedup 1.0000x reference)
//
#include <hip/hip_runtime.h>
#include <math.h>

// Problem dims
#define Bn 8
#define Cn 64
#define Hn 128
#define Wn 128
#define HWn 16384

// ---------------------------------------------------------------------------
// K0: weight prep.
//  w1T[c*1568 + j*32 + co]   <- stn_w1[(co*64+c)*49 + j]      (co fastest)
//  w2T[c*1600 + j*64 + co]   <- stn_w2[(co*32+c)*25 + j]
//  dcnT[(c*9+k)*64 + o]      <- dcn_w[(o*64+c)*9 + k]
//  weff[(c*13+t)*64 + o]     = sum_m w1[o,m]*w3[m,c,tap] (+ w15, w51 branches)
//  beff[o]                   = b1[o] + sum_m w1[o,m]*b3[m] + ... 
// Collapsing the ELK 1x1 into the branch convs is exact (fp32 reassociation).
// ---------------------------------------------------------------------------
__global__ __launch_bounds__(256) void k_prep(
    const float* __restrict__ stn_w1, const float* __restrict__ stn_w2,
    const float* __restrict__ dcn_w,  const float* __restrict__ w3,
    const float* __restrict__ w15,    const float* __restrict__ w51,
    const float* __restrict__ w1,     const float* __restrict__ b3,
    const float* __restrict__ b15,    const float* __restrict__ b51,
    const float* __restrict__ b1,
    float* __restrict__ w1T, float* __restrict__ w2T, float* __restrict__ dcnT,
    float* __restrict__ weff, float* __restrict__ beff)
{
  int e = blockIdx.x * 256 + threadIdx.x;
  if (e < 100352) {                       // w1T
    int co = e & 31, j = (e >> 5) % 49, c = e / 1568;
    w1T[e] = stn_w1[(co * 64 + c) * 49 + j];
    return;
  }
  e -= 100352;
  if (e < 51200) {                        // w2T
    int co = e & 63, j = (e >> 6) % 25, c = e / 1600;
    w2T[e] = stn_w2[(co * 32 + c) * 25 + j];
    return;
  }
  e -= 51200;
  if (e < 36864) {                        // dcnT
    int o = e & 63, k = (e >> 6) % 9, c = e / 576;
    dcnT[e] = dcn_w[(o * 64 + c) * 9 + k];
    return;
  }
  e -= 36864;
  if (e < 53248) {                        // weff (collapsed ELK weights)
    const int DY[13] = {-2,-1,-1,-1, 0, 0, 0, 0, 0, 1, 1, 1, 2};
    const int DX[13] = { 0,-1, 0, 1,-2,-1, 0, 1, 2,-1, 0, 1, 0};
    int o = e & 63, t = (e >> 6) % 13, c = e / 832;
    int dy = DY[t], dx = DX[t];
    float s = 0.f;
    if (dy >= -1 && dy <= 1 && dx >= -1 && dx <= 1) {
      int k3 = (dy + 1) * 3 + (dx + 1);
      for (int m = 0; m < 64; m++) s = fmaf(w1[o * 192 + m], w3[(m * 64 + c) * 9 + k3], s);
    }
    if (dy == 0) {
      int k15 = dx + 2;
      for (int m = 0; m < 64; m++) s = fmaf(w1[o * 192 + 64 + m], w15[(m * 64 + c) * 5 + k15], s);
    }
    if (dx == 0) {
      int k51 = dy + 2;
      for (int m = 0; m < 64; m++) s = fmaf(w1[o * 192 + 128 + m], w51[(m * 64 + c) * 5 + k51], s);
    }
    weff[e] = s;
    return;
  }
  e -= 53248;
  if (e < 64) {                           // beff
    float s = b1[e];
    for (int m = 0; m < 64; m++) {
      s = fmaf(w1[e * 192 + m],       b3[m],  s);
      s = fmaf(w1[e * 192 + 64 + m],  b15[m], s);
      s = fmaf(w1[e * 192 + 128 + m], b51[m], s);
    }
    beff[e] = s;
  }
}

// ---------------------------------------------------------------------------
// K1: STN conv1 7x7 pad3, 64->32, + bias + relu.  Thread = one pixel, acc[32].
// ---------------------------------------------------------------------------
__global__ __launch_bounds__(256) void k_conv1(
    const float* __restrict__ x, const float* __restrict__ w1T,
    const float* __restrict__ b1s, float* __restrict__ t1)
{
  int id = blockIdx.x * 256 + threadIdx.x;
  int wi = id & 127, hi = (id >> 7) & 127, b = id >> 14;
  float acc[32];
#pragma unroll
  for (int o = 0; o < 32; o++) acc[o] = b1s[o];
  const float* xb = x + (size_t)b * Cn * HWn;
  for (int c = 0; c < Cn; c++) {
    const float* xc = xb + c * HWn;
    const float* wc = w1T + c * 1568;
    for (int ky = 0; ky < 7; ky++) {
      int yy = hi + ky - 3;
      int yyc = min(max(yy, 0), 127);
      bool yok = (unsigned)yy < 128u;
#pragma unroll
      for (int kx = 0; kx < 7; kx++) {
        int xx = wi + kx - 3;
        int xxc = min(max(xx, 0), 127);
        float v = xc[yyc * 128 + xxc];
        v = (yok && ((unsigned)xx < 128u)) ? v : 0.f;
        const float4* wp = reinterpret_cast<const float4*>(wc + (ky * 7 + kx) * 32);
#pragma unroll
        for (int o4 = 0; o4 < 8; o4++) {
          float4 wv = wp[o4];
          acc[o4 * 4 + 0] = fmaf(wv.x, v, acc[o4 * 4 + 0]);
          acc[o4 * 4 + 1] = fmaf(wv.y, v, acc[o4 * 4 + 1]);
          acc[o4 * 4 + 2] = fmaf(wv.z, v, acc[o4 * 4 + 2]);
          acc[o4 * 4 + 3] = fmaf(wv.w, v, acc[o4 * 4 + 3]);
        }
      }
    }
  }
  float* ob = t1 + (size_t)b * 32 * HWn + hi * 128 + wi;
#pragma unroll
  for (int o = 0; o < 32; o++) ob[(size_t)o * HWn] = fmaxf(acc[o], 0.f);
}

// ---------------------------------------------------------------------------
// K2: maxpool 2x2 stride 2.
// ---------------------------------------------------------------------------
__global__ __launch_bounds__(256) void k_pool(const float* __restrict__ t1, float* __restrict__ p1)
{
  int id = blockIdx.x * 256 + threadIdx.x;          // 1,048,576 total
  int pw = id & 63, ph = (id >> 6) & 63;
  int bc = id >> 12;                                 // b*32+co
  const float* s = t1 + (size_t)bc * HWn + (ph * 2) * 128 + pw * 2;
  float m0 = fmaxf(s[0], s[1]);
  float m1 = fmaxf(s[128], s[129]);
  p1[id] = fmaxf(m0, m1);
}

// ---------------------------------------------------------------------------
// K3: STN conv2 5x5 pad2, 32->64, +bias+relu, on 64x64. co-split x4 => 512 blocks.
// ---------------------------------------------------------------------------
__global__ __launch_bounds__(256) void k_conv2(
    const float* __restrict__ p1, const float* __restrict__ w2T,
    const float* __restrict__ b2s, float* __restrict__ t2)
{
  int tid = threadIdx.x;
  int tile = blockIdx.x & 15;
  int cs = (blockIdx.x >> 4) & 3;
  int b  = blockIdx.x >> 6;
  int px = tile * 256 + tid;
  int pw = px & 63, ph = px >> 6;
  float acc[16];
#pragma unroll
  for (int o = 0; o < 16; o++) acc[o] = b2s[cs * 16 + o];
  const float* pb = p1 + (size_t)b * 32 * 4096;
  for (int c = 0; c < 32; c++) {
    const float* pc = pb + c * 4096;
    const float* wc = w2T + c * 1600 + cs * 16;
    for (int ky = 0; ky < 5; ky++) {
      int yy = ph + ky - 2;
      int yyc = min(max(yy, 0), 63);
      bool yok = (unsigned)yy < 64u;
#pragma unroll
      for (int kx = 0; kx < 5; kx++) {
        int xx = pw + kx - 2;
        int xxc = min(max(xx, 0), 63);
        float v = pc[yyc * 64 + xxc];
        v = (yok && ((unsigned)xx < 64u)) ? v : 0.f;
        const float4* wp = reinterpret_cast<const float4*>(wc + (ky * 5 + kx) * 64);
#pragma unroll
        for (int o4 = 0; o4 < 4; o4++) {
          float4 wv = wp[o4];
          acc[o4 * 4 + 0] = fmaf(wv.x, v, acc[o4 * 4 + 0]);
          acc[o4 * 4 + 1] = fmaf(wv.y, v, acc[o4 * 4 + 1]);
          acc[o4 * 4 + 2] = fmaf(wv.z, v, acc[o4 * 4 + 2]);
          acc[o4 * 4 + 3] = fmaf(wv.w, v, acc[o4 * 4 + 3]);
        }
      }
    }
  }
  float* ob = t2 + ((size_t)(b * 64 + cs * 16)) * 4096 + ph * 64 + pw;
#pragma unroll
  for (int o = 0; o < 16; o++) ob[(size_t)o * 4096] = fmaxf(acc[o], 0.f);
}

// ---------------------------------------------------------------------------
// K3b: deterministic spatial sum -> feat[b*64+co] (no atomics).
// ---------------------------------------------------------------------------
__global__ __launch_bounds__(256) void k_feat(const float* __restrict__ t2, float* __restrict__ feat)
{
  __shared__ float red[256];
  int bc = blockIdx.x;
  const float* s = t2 + (size_t)bc * 4096;
  float v = 0.f;
  for (int i = threadIdx.x; i < 4096; i += 256) v += s[i];
  red[threadIdx.x] = v;
  __syncthreads();
  for (int st = 128; st > 0; st >>= 1) {
    if (threadIdx.x < st) red[threadIdx.x] += red[threadIdx.x + st];
    __syncthreads();
  }
  if (threadIdx.x == 0) feat[bc] = red[0];
}

// ---------------------------------------------------------------------------
// K4: theta[b,i] = fc_b[i] + (sum_k featsum[b,k]*fc_w[i,k]) / 4096
// ---------------------------------------------------------------------------
__global__ void k_theta(const float* __restrict__ feat, const float* __restrict__ fc_w,
                        const float* __restrict__ fc_b, float* __restrict__ theta)
{
  int tid = threadIdx.x;
  if (tid >= 48) return;
  int b = tid / 6, i = tid - b * 6;
  float s = 0.f;
  for (int k = 0; k < 64; k++) s = fmaf(feat[b * 64 + k], fc_w[i * 64 + k], s);
  theta[tid] = fmaf(s, 1.f / 4096.f, fc_b[i]);
}

// ---------------------------------------------------------------------------
// K5: affine grid + bilinear sample (zeros padding, align_corners=False) -> Fs
// ---------------------------------------------------------------------------
__global__ __launch_bounds__(256) void k_fs(const float* __restrict__ x,
                                            const float* __restrict__ theta,
                                            float* __restrict__ Fs)
{
  int id = blockIdx.x * 256 + threadIdx.x;
  int wi = id & 127, hi = (id >> 7) & 127, b = id >> 14;
  const float* t = theta + b * 6;
  float xn = (float)(2 * wi + 1) * (1.f / 128.f) - 1.f;
  float yn = (float)(2 * hi + 1) * (1.f / 128.f) - 1.f;
  float gx = t[0] * xn + t[1] * yn + t[2];
  float gy = t[3] * xn + t[4] * yn + t[5];
  float ix = fmaf(gx, 64.f, 63.5f);   // ((gx+1)*W - 1)*0.5
  float iy = fmaf(gy, 64.f, 63.5f);

  float y0f = floorf(iy), x0f = floorf(ix);
  float y1f = y0f + 1.f,  x1f = x0f + 1.f;
  float wy1 = iy - y0f, wy0 = 1.f - wy1;
  float wx1 = ix - x0f, wx0 = 1.f - wx1;
  bool vy0 = (y0f >= 0.f) && (y0f <= 127.f);
  bool vy1 = (y1f >= 0.f) && (y1f <= 127.f);
  bool vx0 = (x0f >= 0.f) && (x0f <= 127.f);
  bool vx1 = (x1f >= 0.f) && (x1f <= 127.f);
  int yi0 = (int)fminf(fmaxf(y0f, 0.f), 127.f);
  int yi1 = (int)fminf(fmaxf(y1f, 0.f), 127.f);
  int xi0 = (int)fminf(fmaxf(x0f, 0.f), 127.f);
  int xi1 = (int)fminf(fmaxf(x1f, 0.f), 127.f);
  float w00 = wy0 * wx0 * ((vy0 && vx0) ? 1.f : 0.f);
  float w01 = wy0 * wx1 * ((vy0 && vx1) ? 1.f : 0.f);
  float w10 = wy1 * wx0 * ((vy1 && vx0) ? 1.f : 0.f);
  float w11 = wy1 * wx1 * ((vy1 && vx1) ? 1.f : 0.f);
  int i00 = yi0 * 128 + xi0, i01 = yi0 * 128 + xi1;
  int i10 = yi1 * 128 + xi0, i11 = yi1 * 128 + xi1;

  const float* xb = x + (size_t)b * Cn * HWn;
  float* fb = Fs + (size_t)b * Cn * HWn + hi * 128 + wi;
  for (int c = 0; c < Cn; c++) {
    const float* base = xb + c * HWn;
    float v = w00 * base[i00] + w01 * base[i01] + w10 * base[i10] + w11 * base[i11];
    fb[(size_t)c * HWn] = v;
  }
}

// ---------------------------------------------------------------------------
// K6: deformable conv. Thread = pixel, acc[64] over output channels.
// ---------------------------------------------------------------------------
__global__ __launch_bounds__(256) void k_dcn(const float* __restrict__ x,
                                             const float* __restrict__ off,
                                             const float* __restrict__ dcnT,
                                             const float* __restrict__ dcn_b,
                                             float* __restrict__ Fd)
{
  int id = blockIdx.x * 256 + threadIdx.x;
  int wi = id & 127, hi = (id >> 7) & 127, b = id >> 14;
  float acc[64];
#pragma unroll
  for (int o = 0; o < 64; o++) acc[o] = dcn_b[o];
  const float* xb = x + (size_t)b * Cn * HWn;
  const float* ob = off + (size_t)b * 18 * HWn + hi * 128 + wi;
  for (int k = 0; k < 9; k++) {
    float dy = ob[(size_t)(2 * k) * HWn];
    float dx = ob[(size_t)(2 * k + 1) * HWn];
    float sy = (float)(hi + k / 3 - 1) + dy;
    float sx = (float)(wi + (k % 3) - 1) + dx;

    float y0f = floorf(sy), x0f = floorf(sx);
    float y1f = y0f + 1.f,  x1f = x0f + 1.f;
    float wy1 = sy - y0f, wy0 = 1.f - wy1;
    float wx1 = sx - x0f, wx0 = 1.f - wx1;
    bool vy0 = (y0f >= 0.f) && (y0f <= 127.f);
    bool vy1 = (y1f >= 0.f) && (y1f <= 127.f);
    bool vx0 = (x0f >= 0.f) && (x0f <= 127.f);
    bool vx1 = (x1f >= 0.f) && (x1f <= 127.f);
    int yi0 = (int)fminf(fmaxf(y0f, 0.f), 127.f);
    int yi1 = (int)fminf(fmaxf(y1f, 0.f), 127.f);
    int xi0 = (int)fminf(fmaxf(x0f, 0.f), 127.f);
    int xi1 = (int)fminf(fmaxf(x1f, 0.f), 127.f);
    float w00 = wy0 * wx0 * ((vy0 && vx0) ? 1.f : 0.f);
    float w01 = wy0 * wx1 * ((vy0 && vx1) ? 1.f : 0.f);
    float w10 = wy1 * wx0 * ((vy1 && vx0) ? 1.f : 0.f);
    float w11 = wy1 * wx1 * ((vy1 && vx1) ? 1.f : 0.f);
    int i00 = yi0 * 128 + xi0, i01 = yi0 * 128 + xi1;
    int i10 = yi1 * 128 + xi0, i11 = yi1 * 128 + xi1;

    const float* wkb = dcnT + k * 64;
    for (int c = 0; c < Cn; c++) {
      const float* base = xb + c * HWn;
      float s = w00 * base[i00] + w01 * base[i01] + w10 * base[i10] + w11 * base[i11];
      const float4* wp = reinterpret_cast<const float4*>(wkb + c * 576);
#pragma unroll
      for (int o4 = 0; o4 < 16; o4++) {
        float4 wv = wp[o4];
        acc[o4 * 4 + 0] = fmaf(wv.x, s, acc[o4 * 4 + 0]);
        acc[o4 * 4 + 1] = fmaf(wv.y, s, acc[o4 * 4 + 1]);
        acc[o4 * 4 + 2] = fmaf(wv.z, s, acc[o4 * 4 + 2]);
        acc[o4 * 4 + 3] = fmaf(wv.w, s, acc[o4 * 4 + 3]);
      }
    }
  }
  float* fb = Fd + (size_t)b * Cn * HWn + hi * 128 + wi;
#pragma unroll
  for (int o = 0; o < 64; o++) fb[(size_t)o * HWn] = acc[o];
}

// ---------------------------------------------------------------------------
// K7: softmax-weighted fusion, in place into Fs.
// ---------------------------------------------------------------------------
__global__ __launch_bounds__(256) void k_fuse(float* __restrict__ Fs, const float* __restrict__ Fd,
                                              const float* __restrict__ wg_w,
                                              const float* __restrict__ wg_b)
{
  int id = blockIdx.x * 256 + threadIdx.x;
  int wi = id & 127, hi = (id >> 7) & 127, b = id >> 14;
  size_t p = (size_t)b * Cn * HWn + hi * 128 + wi;
  float fs[64], fd[64];
  float s0 = wg_b[0], s1 = wg_b[1];
#pragma unroll
  for (int c = 0; c < 64; c++) {
    fs[c] = Fs[p + (size_t)c * HWn];
    fd[c] = Fd[p + (size_t)c * HWn];
    s0 = fmaf(wg_w[c],       fs[c], fmaf(wg_w[64 + c],  fd[c], s0));
    s1 = fmaf(wg_w[128 + c], fs[c], fmaf(wg_w[192 + c], fd[c], s1));
  }
  float p0 = 1.f / (1.f + __expf(s1 - s0));   // softmax over 2 channels
  float p1 = 1.f - p0;
#pragma unroll
  for (int c = 0; c < 64; c++) Fs[p + (size_t)c * HWn] = p0 * fs[c] + p1 * fd[c];
}

// ---------------------------------------------------------------------------
// K8: collapsed ELK block: single 13-tap cross conv with weff, bias beff.
// ---------------------------------------------------------------------------
__global__ __launch_bounds__(256) void k_elk(const float* __restrict__ fused,
                                             const float* __restrict__ weff,
                                             const float* __restrict__ beff,
                                             float* __restrict__ out)
{
  const int DY[13] = {-2,-1,-1,-1, 0, 0, 0, 0, 0, 1, 1, 1, 2};
  const int DX[13] = { 0,-1, 0, 1,-2,-1, 0, 1, 2,-1, 0, 1, 0};
  int id = blockIdx.x * 256 + threadIdx.x;
  int wi = id & 127, hi = (id >> 7) & 127, b = id >> 14;
  float acc[64];
#pragma unroll
  for (int o = 0; o < 64; o++) acc[o] = beff[o];
  int toff[13];
  float msk[13];
#pragma unroll
  for (int t = 0; t < 13; t++) {
    int yy = hi + DY[t], xx = wi + DX[t];
    bool ok = ((unsigned)yy < 128u) && ((unsigned)xx < 128u);
    toff[t] = ok ? yy * 128 + xx : 0;
    msk[t] = ok ? 1.f : 0.f;
  }
  const float* fb = fused + (size_t)b * Cn * HWn;
  for (int c = 0; c < 64; c++) {
    const float* base = fb + c * HWn;
    const float* wb = weff + c * 832;
#pragma unroll
    for (int t = 0; t < 13; t++) {
      float v = base[toff[t]] * msk[t];
      const float4* wp = reinterpret_cast<const float4*>(wb + t * 64);
#pragma unroll
      for (int o4 = 0; o4 < 16; o4++) {
        float4 wv = wp[o4];
        acc[o4 * 4 + 0] = fmaf(wv.x, v, acc[o4 * 4 + 0]);
        acc[o4 * 4 + 1] = fmaf(wv.y, v, acc[o4 * 4 + 1]);
        acc[o4 * 4 + 2] = fmaf(wv.z, v, acc[o4 * 4 + 2]);
        acc[o4 * 4 + 3] = fmaf(wv.w, v, acc[o4 * 4 + 3]);
      }
    }
  }
  float* od = out + (size_t)b * Cn * HWn + hi * 128 + wi;
#pragma unroll
  for (int o = 0; o < 64; o++) od[(size_t)o * HWn] = acc[o];
}

// ---------------------------------------------------------------------------
// Launch. Workspace layout (floats):
//  [0, 8388608)          Fs   (also hosts t1[0,4194304) and via t2 reuse; all
//                              STN temporaries are dead before k_fs writes Fs)
//  [4194304, 5242880)    p1
//  [8388608, 16777216)   Fd
//  [16777216, ...)       feat(512), theta(64), w1T, w2T, dcnT, weff, beff
//  total ~65 MiB
// ---------------------------------------------------------------------------
extern "C" void kernel_launch(void* const* d_in, const int* in_sizes, int n_in,
                              void* d_out, int out_size, void* d_ws, size_t ws_size,
                              hipStream_t stream)
{
  (void)in_sizes; (void)n_in; (void)out_size; (void)ws_size;
  const float* x      = (const float*)d_in[0];
  const float* offset = (const float*)d_in[1];
  const float* stn_w1 = (const float*)d_in[2];
  const float* stn_b1 = (const float*)d_in[3];
  const float* stn_w2 = (const float*)d_in[4];
  const float* stn_b2 = (const float*)d_in[5];
  const float* fc_w   = (const float*)d_in[6];
  const float* fc_b   = (const float*)d_in[7];
  const float* dcn_w  = (const float*)d_in[8];
  const float* dcn_b  = (const float*)d_in[9];
  const float* wg_w   = (const float*)d_in[10];
  const float* wg_b   = (const float*)d_in[11];
  const float* w3     = (const float*)d_in[12];
  const float* b3     = (const float*)d_in[13];
  const float* w15    = (const float*)d_in[14];
  const float* b15    = (const float*)d_in[15];
  const float* w51    = (const float*)d_in[16];
  const float* b51    = (const float*)d_in[17];
  const float* w1     = (const float*)d_in[18];
  const float* b1     = (const float*)d_in[19];

  float* ws    = (float*)d_ws;
  float* Fs    = ws;                    // 8,388,608
  float* t1    = ws;                    // 4,194,304 (dead before k_fs)
  float* p1    = ws + 4194304;          // 1,048,576 (dead before k_fs)
  float* t2    = ws;                    // 2,097,152 (reuses t1; dead before k_fs)
  float* Fd    = ws + 8388608;          // 8,388,608
  float* feat  = ws + 16777216;         // 512
  float* theta = ws + 16777728;         // 48 (padded to 64)
  float* w1T   = ws + 16777792;         // 100,352
  float* w2T   = ws + 16878144;         // 51,200
  float* dcnT  = ws + 16929344;         // 36,864
  float* weff  = ws + 16966208;         // 53,248
  float* beff  = ws + 17019456;         // 64
  float* out   = (float*)d_out;

  k_prep <<<945,  256, 0, stream>>>(stn_w1, stn_w2, dcn_w, w3, w15, w51, w1,
                                    b3, b15, b51, b1, w1T, w2T, dcnT, weff, beff);
  k_conv1<<<512,  256, 0, stream>>>(x, w1T, stn_b1, t1);
  k_pool <<<4096, 256, 0, stream>>>(t1, p1);
  k_conv2<<<512,  256, 0, stream>>>(p1, w2T, stn_b2, t2);
  k_feat <<<512,  256, 0, stream>>>(t2, feat);
  k_theta<<<1,    64,  0, stream>>>(feat, fc_w, fc_b, theta);
  k_fs   <<<512,  256, 0, stream>>>(x, theta, Fs);
  k_dcn  <<<512,  256, 0, stream>>>(x, offset, dcnT, dcn_b, Fd);
  k_fuse <<<512,  256, 0, stream>>>(Fs, Fd, wg_w, wg_b);
  k_elk  <<<512,  256, 0, stream>>>(Fs, weff, beff, out);
}

// Round 2
// 776.420 us; speedup vs baseline: 1.5634x; 1.5634x over previous
//
#include <hip/hip_runtime.h>
#include <math.h>

// Problem dims
#define Bn 8
#define Cn 64
#define Hn 128
#define Wn 128
#define HWn 16384

typedef __attribute__((ext_vector_type(8))) __bf16 bf16x8;
typedef __attribute__((ext_vector_type(4))) float f32x4;

// ---------------------------------------------------------------------------
// K0: weight prep (w2T/dcnT/weff/beff as before; w1T retained but unused).
// ---------------------------------------------------------------------------
__global__ __launch_bounds__(256) void k_prep(
    const float* __restrict__ stn_w1, const float* __restrict__ stn_w2,
    const float* __restrict__ dcn_w,  const float* __restrict__ w3,
    const float* __restrict__ w15,    const float* __restrict__ w51,
    const float* __restrict__ w1,     const float* __restrict__ b3,
    const float* __restrict__ b15,    const float* __restrict__ b51,
    const float* __restrict__ b1,
    float* __restrict__ w1T, float* __restrict__ w2T, float* __restrict__ dcnT,
    float* __restrict__ weff, float* __restrict__ beff)
{
  int e = blockIdx.x * 256 + threadIdx.x;
  if (e < 100352) {                       // w1T (unused by MFMA path, kept)
    int co = e & 31, j = (e >> 5) % 49, c = e / 1568;
    w1T[e] = stn_w1[(co * 64 + c) * 49 + j];
    return;
  }
  e -= 100352;
  if (e < 51200) {                        // w2T
    int co = e & 63, j = (e >> 6) % 25, c = e / 1600;
    w2T[e] = stn_w2[(co * 32 + c) * 25 + j];
    return;
  }
  e -= 51200;
  if (e < 36864) {                        // dcnT
    int o = e & 63, k = (e >> 6) % 9, c = e / 576;
    dcnT[e] = dcn_w[(o * 64 + c) * 9 + k];
    return;
  }
  e -= 36864;
  if (e < 53248) {                        // weff (collapsed ELK weights)
    const int DY[13] = {-2,-1,-1,-1, 0, 0, 0, 0, 0, 1, 1, 1, 2};
    const int DX[13] = { 0,-1, 0, 1,-2,-1, 0, 1, 2,-1, 0, 1, 0};
    int o = e & 63, t = (e >> 6) % 13, c = e / 832;
    int dy = DY[t], dx = DX[t];
    float s = 0.f;
    if (dy >= -1 && dy <= 1 && dx >= -1 && dx <= 1) {
      int k3 = (dy + 1) * 3 + (dx + 1);
      for (int m = 0; m < 64; m++) s = fmaf(w1[o * 192 + m], w3[(m * 64 + c) * 9 + k3], s);
    }
    if (dy == 0) {
      int k15 = dx + 2;
      for (int m = 0; m < 64; m++) s = fmaf(w1[o * 192 + 64 + m], w15[(m * 64 + c) * 5 + k15], s);
    }
    if (dx == 0) {
      int k51 = dy + 2;
      for (int m = 0; m < 64; m++) s = fmaf(w1[o * 192 + 128 + m], w51[(m * 64 + c) * 5 + k51], s);
    }
    weff[e] = s;
    return;
  }
  e -= 53248;
  if (e < 64) {                           // beff
    float s = b1[e];
    for (int m = 0; m < 64; m++) {
      s = fmaf(w1[e * 192 + m],       b3[m],  s);
      s = fmaf(w1[e * 192 + 64 + m],  b15[m], s);
      s = fmaf(w1[e * 192 + 128 + m], b51[m], s);
    }
    beff[e] = s;
  }
}

// ---------------------------------------------------------------------------
// K-xt: x (NCHW f32) -> xT[b][hp 134][wp 134][c 64] bf16, zero-padded 3 ring.
// ---------------------------------------------------------------------------
__global__ __launch_bounds__(256) void k_xt(const float* __restrict__ x,
                                            __bf16* __restrict__ xT)
{
  int t = blockIdx.x * 256 + threadIdx.x;
  if (t >= 8 * 134 * 134) return;
  int wp = t % 134;
  int hp = (t / 134) % 134;
  int b  = t / (134 * 134);
  __bf16* dst = xT + (size_t)t * 64;
  int h = hp - 3, w = wp - 3;
  bool inb = ((unsigned)h < 128u) && ((unsigned)w < 128u);
  const float* xb = x + (size_t)b * Cn * HWn + h * 128 + w;
#pragma unroll 2
  for (int c8 = 0; c8 < 8; c8++) {
    bf16x8 v;
#pragma unroll
    for (int j = 0; j < 8; j++)
      v[j] = inb ? (__bf16)xb[(size_t)(c8 * 8 + j) * HWn] : (__bf16)0.f;
    *(bf16x8*)(dst + c8 * 8) = v;
  }
}

// ---------------------------------------------------------------------------
// K-wf: stn_w1 -> A-fragment layout for mfma_f32_16x16x32_bf16.
// wfrag[((tap*2+ck)*2+o16)*64 + lane][e] = W[o16*16+(lane&15)][ck*32+(lane>>4)*8+e]
// ---------------------------------------------------------------------------
__global__ __launch_bounds__(256) void k_wf(const float* __restrict__ stn_w1,
                                            __bf16* __restrict__ wfrag)
{
  int t = blockIdx.x * 256 + threadIdx.x;
  if (t >= 100352) return;
  int e   = t & 7;
  int l   = (t >> 3) & 63;
  int o16 = (t >> 9) & 1;
  int ck  = (t >> 10) & 1;
  int tap = t >> 11;
  int o = o16 * 16 + (l & 15);
  int c = ck * 32 + (l >> 4) * 8 + e;
  wfrag[t] = (__bf16)stn_w1[(o * 64 + c) * 49 + tap];
}

// ---------------------------------------------------------------------------
// K1: STN conv1 via MFMA. Block = 2 waves = 2 output rows; wave tile =
// 32 out x 128 px. LDS x-tile: [q4][r8][wx144] of 16B (8 ch) slots = 72 KB,
// staged with global_load_lds(16B). K-chunks of 32 ch, restaged per chunk.
// ---------------------------------------------------------------------------
__global__ __launch_bounds__(128) void k_conv1m(
    const __bf16* __restrict__ xT, const __bf16* __restrict__ wfrag,
    const float* __restrict__ b1s, float* __restrict__ t1)
{
  __shared__ alignas(16) char tile[73728];   // 4*8*144*16
  const int lane = threadIdx.x & 63;
  const int wv   = threadIdx.x >> 6;         // 0,1
  const int b    = blockIdx.x >> 6;
  const int h0   = (blockIdx.x & 63) * 2;

  f32x4 acc[2][8];
#pragma unroll
  for (int o16 = 0; o16 < 2; o16++)
#pragma unroll
    for (int nf = 0; nf < 8; nf++) acc[o16][nf] = (f32x4){0.f, 0.f, 0.f, 0.f};

  const bf16x8* wf = (const bf16x8*)wfrag;
  const char* tb = (const char*)tile;
  const char* xTb = (const char*)xT;

  for (int ck = 0; ck < 2; ck++) {
    int c0 = ck * 32;
    // ---- stage: 72 x 1KB global_load_lds, split across the 2 waves ----
    for (int i = wv; i < 72; i += 2) {
      int q   = i / 18;
      int rem = i - q * 18;
      int rg  = rem / 9;
      int j   = rem - rg * 9;
      int d   = j * 1024 + lane * 16;       // byte within 4-row quarter group
      int rloc = d / 2304;
      int drem = d - rloc * 2304;
      int wx  = drem >> 4;
      int r   = rg * 4 + rloc;
      const char* src = xTb
          + ((size_t)((b * 134 + h0 + r) * 134 + wx)) * 128 + c0 * 2 + q * 16;
      char* dst = (char*)tile + i * 1024;   // wave-uniform base
      __builtin_amdgcn_global_load_lds(
          (const __attribute__((address_space(1))) void*)src,
          (__attribute__((address_space(3))) void*)dst, 16, 0, 0);
    }
    __syncthreads();

    // ---- 49 taps x 16 MFMA ----
    for (int tap = 0; tap < 49; tap++) {
      int dy7 = tap / 7;          // dy+3
      int dx7 = tap - dy7 * 7;    // dx+3
      bf16x8 a0 = wf[((tap * 2 + ck) * 2 + 0) * 64 + lane];
      bf16x8 a1 = wf[((tap * 2 + ck) * 2 + 1) * 64 + lane];
      const char* bp = tb + (lane >> 4) * 18432 + (wv + dy7) * 2304
                          + (dx7 + (lane & 15)) * 16;
#pragma unroll
      for (int nf = 0; nf < 8; nf++) {
        bf16x8 bv = *(const bf16x8*)(bp + nf * 256);
        acc[0][nf] = __builtin_amdgcn_mfma_f32_16x16x32_bf16(a0, bv, acc[0][nf], 0, 0, 0);
        acc[1][nf] = __builtin_amdgcn_mfma_f32_16x16x32_bf16(a1, bv, acc[1][nf], 0, 0, 0);
      }
    }
    __syncthreads();
  }

  // ---- epilogue: bias + relu, NCHW store ----
#pragma unroll
  for (int o16 = 0; o16 < 2; o16++)
#pragma unroll
    for (int r = 0; r < 4; r++) {
      int o = o16 * 16 + ((lane >> 4) << 2) + r;
      float bb = b1s[o];
      float* orow = t1 + ((size_t)(b * 32 + o)) * HWn + (h0 + wv) * 128 + (lane & 15);
#pragma unroll
      for (int nf = 0; nf < 8; nf++)
        orow[nf * 16] = fmaxf(acc[o16][nf][r] + bb, 0.f);
    }
}

// ---------------------------------------------------------------------------
// K2: maxpool 2x2 stride 2.
// ---------------------------------------------------------------------------
__global__ __launch_bounds__(256) void k_pool(const float* __restrict__ t1, float* __restrict__ p1)
{
  int id = blockIdx.x * 256 + threadIdx.x;
  int pw = id & 63, ph = (id >> 6) & 63;
  int bc = id >> 12;
  const float* s = t1 + (size_t)bc * HWn + (ph * 2) * 128 + pw * 2;
  float m0 = fmaxf(s[0], s[1]);
  float m1 = fmaxf(s[128], s[129]);
  p1[id] = fmaxf(m0, m1);
}

// ---------------------------------------------------------------------------
// K3: STN conv2 5x5 pad2, 32->64, +bias+relu, on 64x64.
// ---------------------------------------------------------------------------
__global__ __launch_bounds__(256) void k_conv2(
    const float* __restrict__ p1, const float* __restrict__ w2T,
    const float* __restrict__ b2s, float* __restrict__ t2)
{
  int tid = threadIdx.x;
  int tile = blockIdx.x & 15;
  int cs = (blockIdx.x >> 4) & 3;
  int b  = blockIdx.x >> 6;
  int px = tile * 256 + tid;
  int pw = px & 63, ph = px >> 6;
  float acc[16];
#pragma unroll
  for (int o = 0; o < 16; o++) acc[o] = b2s[cs * 16 + o];
  const float* pb = p1 + (size_t)b * 32 * 4096;
  for (int c = 0; c < 32; c++) {
    const float* pc = pb + c * 4096;
    const float* wc = w2T + c * 1600 + cs * 16;
    for (int ky = 0; ky < 5; ky++) {
      int yy = ph + ky - 2;
      int yyc = min(max(yy, 0), 63);
      bool yok = (unsigned)yy < 64u;
#pragma unroll
      for (int kx = 0; kx < 5; kx++) {
        int xx = pw + kx - 2;
        int xxc = min(max(xx, 0), 63);
        float v = pc[yyc * 64 + xxc];
        v = (yok && ((unsigned)xx < 64u)) ? v : 0.f;
        const float4* wp = reinterpret_cast<const float4*>(wc + (ky * 5 + kx) * 64);
#pragma unroll
        for (int o4 = 0; o4 < 4; o4++) {
          float4 wv = wp[o4];
          acc[o4 * 4 + 0] = fmaf(wv.x, v, acc[o4 * 4 + 0]);
          acc[o4 * 4 + 1] = fmaf(wv.y, v, acc[o4 * 4 + 1]);
          acc[o4 * 4 + 2] = fmaf(wv.z, v, acc[o4 * 4 + 2]);
          acc[o4 * 4 + 3] = fmaf(wv.w, v, acc[o4 * 4 + 3]);
        }
      }
    }
  }
  float* ob = t2 + ((size_t)(b * 64 + cs * 16)) * 4096 + ph * 64 + pw;
#pragma unroll
  for (int o = 0; o < 16; o++) ob[(size_t)o * 4096] = fmaxf(acc[o], 0.f);
}

// ---------------------------------------------------------------------------
// K3b: deterministic spatial sum -> feat[b*64+co].
// ---------------------------------------------------------------------------
__global__ __launch_bounds__(256) void k_feat(const float* __restrict__ t2, float* __restrict__ feat)
{
  __shared__ float red[256];
  int bc = blockIdx.x;
  const float* s = t2 + (size_t)bc * 4096;
  float v = 0.f;
  for (int i = threadIdx.x; i < 4096; i += 256) v += s[i];
  red[threadIdx.x] = v;
  __syncthreads();
  for (int st = 128; st > 0; st >>= 1) {
    if (threadIdx.x < st) red[threadIdx.x] += red[threadIdx.x + st];
    __syncthreads();
  }
  if (threadIdx.x == 0) feat[bc] = red[0];
}

// ---------------------------------------------------------------------------
// K4: theta
// ---------------------------------------------------------------------------
__global__ void k_theta(const float* __restrict__ feat, const float* __restrict__ fc_w,
                        const float* __restrict__ fc_b, float* __restrict__ theta)
{
  int tid = threadIdx.x;
  if (tid >= 48) return;
  int b = tid / 6, i = tid - b * 6;
  float s = 0.f;
  for (int k = 0; k < 64; k++) s = fmaf(feat[b * 64 + k], fc_w[i * 64 + k], s);
  theta[tid] = fmaf(s, 1.f / 4096.f, fc_b[i]);
}

// ---------------------------------------------------------------------------
// K5: affine grid + bilinear sample -> Fs
// ---------------------------------------------------------------------------
__global__ __launch_bounds__(256) void k_fs(const float* __restrict__ x,
                                            const float* __restrict__ theta,
                                            float* __restrict__ Fs)
{
  int id = blockIdx.x * 256 + threadIdx.x;
  int wi = id & 127, hi = (id >> 7) & 127, b = id >> 14;
  const float* t = theta + b * 6;
  float xn = (float)(2 * wi + 1) * (1.f / 128.f) - 1.f;
  float yn = (float)(2 * hi + 1) * (1.f / 128.f) - 1.f;
  float gx = t[0] * xn + t[1] * yn + t[2];
  float gy = t[3] * xn + t[4] * yn + t[5];
  float ix = fmaf(gx, 64.f, 63.5f);
  float iy = fmaf(gy, 64.f, 63.5f);

  float y0f = floorf(iy), x0f = floorf(ix);
  float y1f = y0f + 1.f,  x1f = x0f + 1.f;
  float wy1 = iy - y0f, wy0 = 1.f - wy1;
  float wx1 = ix - x0f, wx0 = 1.f - wx1;
  bool vy0 = (y0f >= 0.f) && (y0f <= 127.f);
  bool vy1 = (y1f >= 0.f) && (y1f <= 127.f);
  bool vx0 = (x0f >= 0.f) && (x0f <= 127.f);
  bool vx1 = (x1f >= 0.f) && (x1f <= 127.f);
  int yi0 = (int)fminf(fmaxf(y0f, 0.f), 127.f);
  int yi1 = (int)fminf(fmaxf(y1f, 0.f), 127.f);
  int xi0 = (int)fminf(fmaxf(x0f, 0.f), 127.f);
  int xi1 = (int)fminf(fmaxf(x1f, 0.f), 127.f);
  float w00 = wy0 * wx0 * ((vy0 && vx0) ? 1.f : 0.f);
  float w01 = wy0 * wx1 * ((vy0 && vx1) ? 1.f : 0.f);
  float w10 = wy1 * wx0 * ((vy1 && vx0) ? 1.f : 0.f);
  float w11 = wy1 * wx1 * ((vy1 && vx1) ? 1.f : 0.f);
  int i00 = yi0 * 128 + xi0, i01 = yi0 * 128 + xi1;
  int i10 = yi1 * 128 + xi0, i11 = yi1 * 128 + xi1;

  const float* xb = x + (size_t)b * Cn * HWn;
  float* fb = Fs + (size_t)b * Cn * HWn + hi * 128 + wi;
  for (int c = 0; c < Cn; c++) {
    const float* base = xb + c * HWn;
    float v = w00 * base[i00] + w01 * base[i01] + w10 * base[i10] + w11 * base[i11];
    fb[(size_t)c * HWn] = v;
  }
}

// ---------------------------------------------------------------------------
// K6: deformable conv, fp32.
// ---------------------------------------------------------------------------
__global__ __launch_bounds__(256) void k_dcn(const float* __restrict__ x,
                                             const float* __restrict__ off,
                                             const float* __restrict__ dcnT,
                                             const float* __restrict__ dcn_b,
                                             float* __restrict__ Fd)
{
  int id = blockIdx.x * 256 + threadIdx.x;
  int wi = id & 127, hi = (id >> 7) & 127, b = id >> 14;
  float acc[64];
#pragma unroll
  for (int o = 0; o < 64; o++) acc[o] = dcn_b[o];
  const float* xb = x + (size_t)b * Cn * HWn;
  const float* ob = off + (size_t)b * 18 * HWn + hi * 128 + wi;
  for (int k = 0; k < 9; k++) {
    float dy = ob[(size_t)(2 * k) * HWn];
    float dx = ob[(size_t)(2 * k + 1) * HWn];
    float sy = (float)(hi + k / 3 - 1) + dy;
    float sx = (float)(wi + (k % 3) - 1) + dx;

    float y0f = floorf(sy), x0f = floorf(sx);
    float y1f = y0f + 1.f,  x1f = x0f + 1.f;
    float wy1 = sy - y0f, wy0 = 1.f - wy1;
    float wx1 = sx - x0f, wx0 = 1.f - wx1;
    bool vy0 = (y0f >= 0.f) && (y0f <= 127.f);
    bool vy1 = (y1f >= 0.f) && (y1f <= 127.f);
    bool vx0 = (x0f >= 0.f) && (x0f <= 127.f);
    bool vx1 = (x1f >= 0.f) && (x1f <= 127.f);
    int yi0 = (int)fminf(fmaxf(y0f, 0.f), 127.f);
    int yi1 = (int)fminf(fmaxf(y1f, 0.f), 127.f);
    int xi0 = (int)fminf(fmaxf(x0f, 0.f), 127.f);
    int xi1 = (int)fminf(fmaxf(x1f, 0.f), 127.f);
    float w00 = wy0 * wx0 * ((vy0 && vx0) ? 1.f : 0.f);
    float w01 = wy0 * wx1 * ((vy0 && vx1) ? 1.f : 0.f);
    float w10 = wy1 * wx0 * ((vy1 && vx0) ? 1.f : 0.f);
    float w11 = wy1 * wx1 * ((vy1 && vx1) ? 1.f : 0.f);
    int i00 = yi0 * 128 + xi0, i01 = yi0 * 128 + xi1;
    int i10 = yi1 * 128 + xi0, i11 = yi1 * 128 + xi1;

    const float* wkb = dcnT + k * 64;
    for (int c = 0; c < Cn; c++) {
      const float* base = xb + c * HWn;
      float s = w00 * base[i00] + w01 * base[i01] + w10 * base[i10] + w11 * base[i11];
      const float4* wp = reinterpret_cast<const float4*>(wkb + c * 576);
#pragma unroll
      for (int o4 = 0; o4 < 16; o4++) {
        float4 wv = wp[o4];
        acc[o4 * 4 + 0] = fmaf(wv.x, s, acc[o4 * 4 + 0]);
        acc[o4 * 4 + 1] = fmaf(wv.y, s, acc[o4 * 4 + 1]);
        acc[o4 * 4 + 2] = fmaf(wv.z, s, acc[o4 * 4 + 2]);
        acc[o4 * 4 + 3] = fmaf(wv.w, s, acc[o4 * 4 + 3]);
      }
    }
  }
  float* fb = Fd + (size_t)b * Cn * HWn + hi * 128 + wi;
#pragma unroll
  for (int o = 0; o < 64; o++) fb[(size_t)o * HWn] = acc[o];
}

// ---------------------------------------------------------------------------
// K7: softmax-weighted fusion, in place into Fs.
// ---------------------------------------------------------------------------
__global__ __launch_bounds__(256) void k_fuse(float* __restrict__ Fs, const float* __restrict__ Fd,
                                              const float* __restrict__ wg_w,
                                              const float* __restrict__ wg_b)
{
  int id = blockIdx.x * 256 + threadIdx.x;
  int wi = id & 127, hi = (id >> 7) & 127, b = id >> 14;
  size_t p = (size_t)b * Cn * HWn + hi * 128 + wi;
  float fs[64], fd[64];
  float s0 = wg_b[0], s1 = wg_b[1];
#pragma unroll
  for (int c = 0; c < 64; c++) {
    fs[c] = Fs[p + (size_t)c * HWn];
    fd[c] = Fd[p + (size_t)c * HWn];
    s0 = fmaf(wg_w[c],       fs[c], fmaf(wg_w[64 + c],  fd[c], s0));
    s1 = fmaf(wg_w[128 + c], fs[c], fmaf(wg_w[192 + c], fd[c], s1));
  }
  float p0 = 1.f / (1.f + __expf(s1 - s0));
  float p1 = 1.f - p0;
#pragma unroll
  for (int c = 0; c < 64; c++) Fs[p + (size_t)c * HWn] = p0 * fs[c] + p1 * fd[c];
}

// ---------------------------------------------------------------------------
// K8: collapsed ELK block.
// ---------------------------------------------------------------------------
__global__ __launch_bounds__(256) void k_elk(const float* __restrict__ fused,
                                             const float* __restrict__ weff,
                                             const float* __restrict__ beff,
                                             float* __restrict__ out)
{
  const int DY[13] = {-2,-1,-1,-1, 0, 0, 0, 0, 0, 1, 1, 1, 2};
  const int DX[13] = { 0,-1, 0, 1,-2,-1, 0, 1, 2,-1, 0, 1, 0};
  int id = blockIdx.x * 256 + threadIdx.x;
  int wi = id & 127, hi = (id >> 7) & 127, b = id >> 14;
  float acc[64];
#pragma unroll
  for (int o = 0; o < 64; o++) acc[o] = beff[o];
  int toff[13];
  float msk[13];
#pragma unroll
  for (int t = 0; t < 13; t++) {
    int yy = hi + DY[t], xx = wi + DX[t];
    bool ok = ((unsigned)yy < 128u) && ((unsigned)xx < 128u);
    toff[t] = ok ? yy * 128 + xx : 0;
    msk[t] = ok ? 1.f : 0.f;
  }
  const float* fb = fused + (size_t)b * Cn * HWn;
  for (int c = 0; c < 64; c++) {
    const float* base = fb + c * HWn;
    const float* wb = weff + c * 832;
#pragma unroll
    for (int t = 0; t < 13; t++) {
      float v = base[toff[t]] * msk[t];
      const float4* wp = reinterpret_cast<const float4*>(wb + t * 64);
#pragma unroll
      for (int o4 = 0; o4 < 16; o4++) {
        float4 wv = wp[o4];
        acc[o4 * 4 + 0] = fmaf(wv.x, v, acc[o4 * 4 + 0]);
        acc[o4 * 4 + 1] = fmaf(wv.y, v, acc[o4 * 4 + 1]);
        acc[o4 * 4 + 2] = fmaf(wv.z, v, acc[o4 * 4 + 2]);
        acc[o4 * 4 + 3] = fmaf(wv.w, v, acc[o4 * 4 + 3]);
      }
    }
  }
  float* od = out + (size_t)b * Cn * HWn + hi * 128 + wi;
#pragma unroll
  for (int o = 0; o < 64; o++) od[(size_t)o * HWn] = acc[o];
}

// ---------------------------------------------------------------------------
// Launch. Workspace layout (floats):
//  [0, 4194304)          t1 (conv1 out)            -> dead before k_fs
//  [4194304, 5242880)    p1                        -> dead before k_fs
//  [0, 2097152)          t2 (reuses t1)            -> dead before k_fs
//  [5242880, 5293056)    wfrag (conv1 A-frags bf16)-> dead before k_fs
//  [0, 8388608)          Fs (written by k_fs)
//  [8388608, +4595712)   xT bf16 (in Fd region)    -> dead before k_dcn
//  [8388608, 16777216)   Fd (written by k_dcn)
//  [16777216, ...)       feat, theta, w1T, w2T, dcnT, weff, beff
// ---------------------------------------------------------------------------
extern "C" void kernel_launch(void* const* d_in, const int* in_sizes, int n_in,
                              void* d_out, int out_size, void* d_ws, size_t ws_size,
                              hipStream_t stream)
{
  (void)in_sizes; (void)n_in; (void)out_size; (void)ws_size;
  const float* x      = (const float*)d_in[0];
  const float* offset = (const float*)d_in[1];
  const float* stn_w1 = (const float*)d_in[2];
  const float* stn_b1 = (const float*)d_in[3];
  const float* stn_w2 = (const float*)d_in[4];
  const float* stn_b2 = (const float*)d_in[5];
  const float* fc_w   = (const float*)d_in[6];
  const float* fc_b   = (const float*)d_in[7];
  const float* dcn_w  = (const float*)d_in[8];
  const float* dcn_b  = (const float*)d_in[9];
  const float* wg_w   = (const float*)d_in[10];
  const float* wg_b   = (const float*)d_in[11];
  const float* w3     = (const float*)d_in[12];
  const float* b3     = (const float*)d_in[13];
  const float* w15    = (const float*)d_in[14];
  const float* b15    = (const float*)d_in[15];
  const float* w51    = (const float*)d_in[16];
  const float* b51    = (const float*)d_in[17];
  const float* w1     = (const float*)d_in[18];
  const float* b1     = (const float*)d_in[19];

  float* ws    = (float*)d_ws;
  float* Fs    = ws;
  float* t1    = ws;
  float* p1    = ws + 4194304;
  float* t2    = ws;
  __bf16* wfrag= (__bf16*)(ws + 5242880);   // 100,352 bf16 = 200,704 B
  float* Fd    = ws + 8388608;
  __bf16* xT   = (__bf16*)(ws + 8388608);   // 18.4 MB inside Fd region
  float* feat  = ws + 16777216;
  float* theta = ws + 16777728;
  float* w1T   = ws + 16777792;
  float* w2T   = ws + 16878144;
  float* dcnT  = ws + 16929344;
  float* weff  = ws + 16966208;
  float* beff  = ws + 17019456;
  float* out   = (float*)d_out;

  k_prep  <<<945,  256, 0, stream>>>(stn_w1, stn_w2, dcn_w, w3, w15, w51, w1,
                                     b3, b15, b51, b1, w1T, w2T, dcnT, weff, beff);
  k_xt    <<<562,  256, 0, stream>>>(x, xT);
  k_wf    <<<392,  256, 0, stream>>>(stn_w1, wfrag);
  k_conv1m<<<512,  128, 0, stream>>>(xT, wfrag, stn_b1, t1);
  k_pool  <<<4096, 256, 0, stream>>>(t1, p1);
  k_conv2 <<<512,  256, 0, stream>>>(p1, w2T, stn_b2, t2);
  k_feat  <<<512,  256, 0, stream>>>(t2, feat);
  k_theta <<<1,    64,  0, stream>>>(feat, fc_w, fc_b, theta);
  k_fs    <<<512,  256, 0, stream>>>(x, theta, Fs);
  k_dcn   <<<512,  256, 0, stream>>>(x, offset, dcnT, dcn_b, Fd);
  k_fuse  <<<512,  256, 0, stream>>>(Fs, Fd, wg_w, wg_b);
  k_elk   <<<512,  256, 0, stream>>>(Fs, weff, beff, out);
}

// Round 4
// 463.237 us; speedup vs baseline: 2.6204x; 1.6761x over previous
//
#include <hip/hip_runtime.h>
#include <math.h>

// Problem dims
#define Bn 8
#define Cn 64
#define Hn 128
#define Wn 128
#define HWn 16384

typedef __attribute__((ext_vector_type(8))) __bf16 bf16x8;
typedef __attribute__((ext_vector_type(4))) __bf16 bf16x4;
typedef __attribute__((ext_vector_type(4))) float f32x4;

// ---------------------------------------------------------------------------
// K0: weight prep: w2T (conv2 weights, co-fastest) + beff (collapsed ELK bias).
// ---------------------------------------------------------------------------
__global__ __launch_bounds__(256) void k_prep(
    const float* __restrict__ stn_w2, const float* __restrict__ w1,
    const float* __restrict__ b3, const float* __restrict__ b15,
    const float* __restrict__ b51, const float* __restrict__ b1,
    float* __restrict__ w2T, float* __restrict__ beff)
{
  int e = blockIdx.x * 256 + threadIdx.x;
  if (e < 51200) {                        // w2T
    int co = e & 63, j = (e >> 6) % 25, c = e / 1600;
    w2T[e] = stn_w2[(co * 32 + c) * 25 + j];
    return;
  }
  e -= 51200;
  if (e < 64) {                           // beff
    float s = b1[e];
    for (int m = 0; m < 64; m++) {
      s = fmaf(w1[e * 192 + m],       b3[m],  s);
      s = fmaf(w1[e * 192 + 64 + m],  b15[m], s);
      s = fmaf(w1[e * 192 + 128 + m], b51[m], s);
    }
    beff[e] = s;
  }
}

// ---------------------------------------------------------------------------
// K-xt: x (NCHW f32) -> xT[b][hp 134][wp 134][c 64] bf16, zero-padded 3 ring.
// ---------------------------------------------------------------------------
__global__ __launch_bounds__(256) void k_xt(const float* __restrict__ x,
                                            __bf16* __restrict__ xT)
{
  int t = blockIdx.x * 256 + threadIdx.x;
  if (t >= 8 * 134 * 134) return;
  int wp = t % 134;
  int hp = (t / 134) % 134;
  int b  = t / (134 * 134);
  __bf16* dst = xT + (size_t)t * 64;
  int h = hp - 3, w = wp - 3;
  bool inb = ((unsigned)h < 128u) && ((unsigned)w < 128u);
  const float* xb = x + (size_t)b * Cn * HWn + h * 128 + w;
#pragma unroll 2
  for (int c8 = 0; c8 < 8; c8++) {
    bf16x8 v;
#pragma unroll
    for (int j = 0; j < 8; j++)
      v[j] = inb ? (__bf16)xb[(size_t)(c8 * 8 + j) * HWn] : (__bf16)0.f;
    *(bf16x8*)(dst + c8 * 8) = v;
  }
}

// ---------------------------------------------------------------------------
// K-wf: stn_w1 -> A-fragment layout for conv1 MFMA.
// ---------------------------------------------------------------------------
__global__ __launch_bounds__(256) void k_wf(const float* __restrict__ stn_w1,
                                            __bf16* __restrict__ wfrag)
{
  int t = blockIdx.x * 256 + threadIdx.x;
  if (t >= 100352) return;
  int e   = t & 7;
  int l   = (t >> 3) & 63;
  int o16 = (t >> 9) & 1;
  int ck  = (t >> 10) & 1;
  int tap = t >> 11;
  int o = o16 * 16 + (l & 15);
  int c = ck * 32 + (l >> 4) * 8 + e;
  wfrag[t] = (__bf16)stn_w1[(o * 64 + c) * 49 + tap];
}

// ---------------------------------------------------------------------------
// K-frag: A-fragments for DCN (dcnD, 9 taps) and collapsed ELK (weffD, 13 taps).
// Layout: [((tap*2+s)*4+mf)*64 + lane][e]: W[o=mf*16+(l&15)][c=s*32+(l>>4)*8+e].
// ---------------------------------------------------------------------------
__global__ __launch_bounds__(256) void k_frag(
    const float* __restrict__ dcn_w, const float* __restrict__ w1,
    const float* __restrict__ w3, const float* __restrict__ w15,
    const float* __restrict__ w51,
    __bf16* __restrict__ dcnD, __bf16* __restrict__ weffD)
{
  int t = blockIdx.x * 256 + threadIdx.x;
  if (t < 36864) {
    int e = t & 7, l = (t >> 3) & 63, mf = (t >> 9) & 3, s = (t >> 11) & 1;
    int tap = t >> 12;
    int o = mf * 16 + (l & 15), c = s * 32 + (l >> 4) * 8 + e;
    dcnD[t] = (__bf16)dcn_w[(o * 64 + c) * 9 + tap];
    return;
  }
  t -= 36864;
  if (t < 53248) {
    const int DY[13] = {-2,-1,-1,-1, 0, 0, 0, 0, 0, 1, 1, 1, 2};
    const int DX[13] = { 0,-1, 0, 1,-2,-1, 0, 1, 2,-1, 0, 1, 0};
    int e = t & 7, l = (t >> 3) & 63, mf = (t >> 9) & 3, s = (t >> 11) & 1;
    int tap = t >> 12;
    int o = mf * 16 + (l & 15), c = s * 32 + (l >> 4) * 8 + e;
    int dy = DY[tap], dx = DX[tap];
    float v = 0.f;
    if (dy >= -1 && dy <= 1 && dx >= -1 && dx <= 1) {
      int k3 = (dy + 1) * 3 + (dx + 1);
      for (int m = 0; m < 64; m++) v = fmaf(w1[o * 192 + m], w3[(m * 64 + c) * 9 + k3], v);
    }
    if (dy == 0) {
      int k15 = dx + 2;
      for (int m = 0; m < 64; m++) v = fmaf(w1[o * 192 + 64 + m], w15[(m * 64 + c) * 5 + k15], v);
    }
    if (dx == 0) {
      int k51 = dy + 2;
      for (int m = 0; m < 64; m++) v = fmaf(w1[o * 192 + 128 + m], w51[(m * 64 + c) * 5 + k51], v);
    }
    weffD[t] = (__bf16)v;
  }
}

// ---------------------------------------------------------------------------
// K1: STN conv1 via MFMA.
// ---------------------------------------------------------------------------
__global__ __launch_bounds__(128) void k_conv1m(
    const __bf16* __restrict__ xT, const __bf16* __restrict__ wfrag,
    const float* __restrict__ b1s, float* __restrict__ t1)
{
  __shared__ alignas(16) char tile[73728];   // 4*8*144*16
  const int lane = threadIdx.x & 63;
  const int wv   = threadIdx.x >> 6;
  const int b    = blockIdx.x >> 6;
  const int h0   = (blockIdx.x & 63) * 2;

  f32x4 acc[2][8];
#pragma unroll
  for (int o16 = 0; o16 < 2; o16++)
#pragma unroll
    for (int nf = 0; nf < 8; nf++) acc[o16][nf] = (f32x4){0.f, 0.f, 0.f, 0.f};

  const bf16x8* wf = (const bf16x8*)wfrag;
  const char* tb = (const char*)tile;
  const char* xTb = (const char*)xT;

  for (int ck = 0; ck < 2; ck++) {
    int c0 = ck * 32;
    for (int i = wv; i < 72; i += 2) {
      int q   = i / 18;
      int rem = i - q * 18;
      int rg  = rem / 9;
      int j   = rem - rg * 9;
      int d   = j * 1024 + lane * 16;
      int rloc = d / 2304;
      int drem = d - rloc * 2304;
      int wx  = drem >> 4;
      int r   = rg * 4 + rloc;
      const char* src = xTb
          + ((size_t)((b * 134 + h0 + r) * 134 + wx)) * 128 + c0 * 2 + q * 16;
      char* dst = (char*)tile + i * 1024;
      __builtin_amdgcn_global_load_lds(
          (const __attribute__((address_space(1))) void*)src,
          (__attribute__((address_space(3))) void*)dst, 16, 0, 0);
    }
    __syncthreads();

    for (int tap = 0; tap < 49; tap++) {
      int dy7 = tap / 7;
      int dx7 = tap - dy7 * 7;
      bf16x8 a0 = wf[((tap * 2 + ck) * 2 + 0) * 64 + lane];
      bf16x8 a1 = wf[((tap * 2 + ck) * 2 + 1) * 64 + lane];
      const char* bp = tb + (lane >> 4) * 18432 + (wv + dy7) * 2304
                          + (dx7 + (lane & 15)) * 16;
#pragma unroll
      for (int nf = 0; nf < 8; nf++) {
        bf16x8 bv = *(const bf16x8*)(bp + nf * 256);
        acc[0][nf] = __builtin_amdgcn_mfma_f32_16x16x32_bf16(a0, bv, acc[0][nf], 0, 0, 0);
        acc[1][nf] = __builtin_amdgcn_mfma_f32_16x16x32_bf16(a1, bv, acc[1][nf], 0, 0, 0);
      }
    }
    __syncthreads();
  }

#pragma unroll
  for (int o16 = 0; o16 < 2; o16++)
#pragma unroll
    for (int r = 0; r < 4; r++) {
      int o = o16 * 16 + ((lane >> 4) << 2) + r;
      float bb = b1s[o];
      float* orow = t1 + ((size_t)(b * 32 + o)) * HWn + (h0 + wv) * 128 + (lane & 15);
#pragma unroll
      for (int nf = 0; nf < 8; nf++)
        orow[nf * 16] = fmaxf(acc[o16][nf][r] + bb, 0.f);
    }
}

// ---------------------------------------------------------------------------
// K2: maxpool 2x2 stride 2.
// ---------------------------------------------------------------------------
__global__ __launch_bounds__(256) void k_pool(const float* __restrict__ t1, float* __restrict__ p1)
{
  int id = blockIdx.x * 256 + threadIdx.x;
  int pw = id & 63, ph = (id >> 6) & 63;
  int bc = id >> 12;
  const float* s = t1 + (size_t)bc * HWn + (ph * 2) * 128 + pw * 2;
  float m0 = fmaxf(s[0], s[1]);
  float m1 = fmaxf(s[128], s[129]);
  p1[id] = fmaxf(m0, m1);
}

// ---------------------------------------------------------------------------
// K3: STN conv2 5x5 pad2, 32->64, fp32 VALU.
// ---------------------------------------------------------------------------
__global__ __launch_bounds__(256) void k_conv2(
    const float* __restrict__ p1, const float* __restrict__ w2T,
    const float* __restrict__ b2s, float* __restrict__ t2)
{
  int tid = threadIdx.x;
  int tile = blockIdx.x & 15;
  int cs = (blockIdx.x >> 4) & 3;
  int b  = blockIdx.x >> 6;
  int px = tile * 256 + tid;
  int pw = px & 63, ph = px >> 6;
  float acc[16];
#pragma unroll
  for (int o = 0; o < 16; o++) acc[o] = b2s[cs * 16 + o];
  const float* pb = p1 + (size_t)b * 32 * 4096;
  for (int c = 0; c < 32; c++) {
    const float* pc = pb + c * 4096;
    const float* wc = w2T + c * 1600 + cs * 16;
    for (int ky = 0; ky < 5; ky++) {
      int yy = ph + ky - 2;
      int yyc = min(max(yy, 0), 63);
      bool yok = (unsigned)yy < 64u;
#pragma unroll
      for (int kx = 0; kx < 5; kx++) {
        int xx = pw + kx - 2;
        int xxc = min(max(xx, 0), 63);
        float v = pc[yyc * 64 + xxc];
        v = (yok && ((unsigned)xx < 64u)) ? v : 0.f;
        const float4* wp = reinterpret_cast<const float4*>(wc + (ky * 5 + kx) * 64);
#pragma unroll
        for (int o4 = 0; o4 < 4; o4++) {
          float4 wv = wp[o4];
          acc[o4 * 4 + 0] = fmaf(wv.x, v, acc[o4 * 4 + 0]);
          acc[o4 * 4 + 1] = fmaf(wv.y, v, acc[o4 * 4 + 1]);
          acc[o4 * 4 + 2] = fmaf(wv.z, v, acc[o4 * 4 + 2]);
          acc[o4 * 4 + 3] = fmaf(wv.w, v, acc[o4 * 4 + 3]);
        }
      }
    }
  }
  float* ob = t2 + ((size_t)(b * 64 + cs * 16)) * 4096 + ph * 64 + pw;
#pragma unroll
  for (int o = 0; o < 16; o++) ob[(size_t)o * 4096] = fmaxf(acc[o], 0.f);
}

// ---------------------------------------------------------------------------
// K3b: deterministic spatial sum -> feat[b*64+co].
// ---------------------------------------------------------------------------
__global__ __launch_bounds__(256) void k_feat(const float* __restrict__ t2, float* __restrict__ feat)
{
  __shared__ float red[256];
  int bc = blockIdx.x;
  const float* s = t2 + (size_t)bc * 4096;
  float v = 0.f;
  for (int i = threadIdx.x; i < 4096; i += 256) v += s[i];
  red[threadIdx.x] = v;
  __syncthreads();
  for (int st = 128; st > 0; st >>= 1) {
    if (threadIdx.x < st) red[threadIdx.x] += red[threadIdx.x + st];
    __syncthreads();
  }
  if (threadIdx.x == 0) feat[bc] = red[0];
}

// ---------------------------------------------------------------------------
// K4: theta
// ---------------------------------------------------------------------------
__global__ void k_theta(const float* __restrict__ feat, const float* __restrict__ fc_w,
                        const float* __restrict__ fc_b, float* __restrict__ theta)
{
  int tid = threadIdx.x;
  if (tid >= 48) return;
  int b = tid / 6, i = tid - b * 6;
  float s = 0.f;
  for (int k = 0; k < 64; k++) s = fmaf(feat[b * 64 + k], fc_w[i * 64 + k], s);
  theta[tid] = fmaf(s, 1.f / 4096.f, fc_b[i]);
}

// ---------------------------------------------------------------------------
// K5: affine grid + bilinear sample -> FsT bf16 channels-last [b][h][w][64].
// ---------------------------------------------------------------------------
__global__ __launch_bounds__(256) void k_fs(const float* __restrict__ x,
                                            const float* __restrict__ theta,
                                            __bf16* __restrict__ FsT)
{
  int id = blockIdx.x * 256 + threadIdx.x;
  int wi = id & 127, hi = (id >> 7) & 127, b = id >> 14;
  const float* t = theta + b * 6;
  float xn = (float)(2 * wi + 1) * (1.f / 128.f) - 1.f;
  float yn = (float)(2 * hi + 1) * (1.f / 128.f) - 1.f;
  float gx = t[0] * xn + t[1] * yn + t[2];
  float gy = t[3] * xn + t[4] * yn + t[5];
  float ix = fmaf(gx, 64.f, 63.5f);
  float iy = fmaf(gy, 64.f, 63.5f);

  float y0f = floorf(iy), x0f = floorf(ix);
  float y1f = y0f + 1.f,  x1f = x0f + 1.f;
  float wy1 = iy - y0f, wy0 = 1.f - wy1;
  float wx1 = ix - x0f, wx0 = 1.f - wx1;
  bool vy0 = (y0f >= 0.f) && (y0f <= 127.f);
  bool vy1 = (y1f >= 0.f) && (y1f <= 127.f);
  bool vx0 = (x0f >= 0.f) && (x0f <= 127.f);
  bool vx1 = (x1f >= 0.f) && (x1f <= 127.f);
  int yi0 = (int)fminf(fmaxf(y0f, 0.f), 127.f);
  int yi1 = (int)fminf(fmaxf(y1f, 0.f), 127.f);
  int xi0 = (int)fminf(fmaxf(x0f, 0.f), 127.f);
  int xi1 = (int)fminf(fmaxf(x1f, 0.f), 127.f);
  float w00 = wy0 * wx0 * ((vy0 && vx0) ? 1.f : 0.f);
  float w01 = wy0 * wx1 * ((vy0 && vx1) ? 1.f : 0.f);
  float w10 = wy1 * wx0 * ((vy1 && vx0) ? 1.f : 0.f);
  float w11 = wy1 * wx1 * ((vy1 && vx1) ? 1.f : 0.f);
  int i00 = yi0 * 128 + xi0, i01 = yi0 * 128 + xi1;
  int i10 = yi1 * 128 + xi0, i11 = yi1 * 128 + xi1;

  const float* xb = x + (size_t)b * Cn * HWn;
  __bf16* dst = FsT + ((size_t)b * HWn + hi * 128 + wi) * 64;
#pragma unroll 2
  for (int oct = 0; oct < 8; oct++) {
    bf16x8 r;
#pragma unroll
    for (int j = 0; j < 8; j++) {
      const float* base = xb + (size_t)(oct * 8 + j) * HWn;
      float v = w00 * base[i00] + w01 * base[i01] + w10 * base[i10] + w11 * base[i11];
      r[j] = (__bf16)v;
    }
    *(bf16x8*)(dst + oct * 8) = r;
  }
}

// ---------------------------------------------------------------------------
// K6: deformable conv via MFMA. Wave = 64 px (half row) x 64 out-ch.
// ---------------------------------------------------------------------------
__global__ __launch_bounds__(256) void k_dcnm(
    const __bf16* __restrict__ xT, const float* __restrict__ off,
    const __bf16* __restrict__ dcnD, const float* __restrict__ dcn_b,
    __bf16* __restrict__ FdT)
{
  __shared__ alignas(16) char smem[4][8192];
  const int lane = threadIdx.x & 63;
  const int wv   = threadIdx.x >> 6;
  const int b    = blockIdx.x >> 6;
  const int h    = (blockIdx.x & 63) * 2 + (wv >> 1);
  const int half = wv & 1;
  const int w    = half * 64 + lane;

  f32x4 acc[4][4];
#pragma unroll
  for (int mf = 0; mf < 4; mf++)
#pragma unroll
    for (int nf = 0; nf < 4; nf++) acc[mf][nf] = (f32x4){0.f, 0.f, 0.f, 0.f};

  const float* ob = off + (size_t)b * 18 * HWn + h * 128 + w;
  char* sm = smem[wv];
  const bf16x8* aD = (const bf16x8*)dcnD;
  const __bf16* xb = xT + (size_t)b * 134 * 134 * 64;

  for (int k = 0; k < 9; k++) {
    float dy = ob[(size_t)(2 * k) * HWn];
    float dx = ob[(size_t)(2 * k + 1) * HWn];
    float sy = (float)(h + k / 3 - 1) + dy;
    float sx = (float)(w + (k % 3) - 1) + dx;

    float y0f = floorf(sy), x0f = floorf(sx);
    float wy1 = sy - y0f, wy0 = 1.f - wy1;
    float wx1 = sx - x0f, wx0 = 1.f - wx1;
    bool vy0 = (y0f >= 0.f) && (y0f <= 127.f);
    bool vy1 = (y0f >= -1.f) && (y0f <= 126.f);
    bool vx0 = (x0f >= 0.f) && (x0f <= 127.f);
    bool vx1 = (x0f >= -1.f) && (x0f <= 126.f);
    int yi0 = (int)fminf(fmaxf(y0f, 0.f), 127.f);
    int yi1 = (int)fminf(fmaxf(y0f + 1.f, 0.f), 127.f);
    int xi0 = (int)fminf(fmaxf(x0f, 0.f), 127.f);
    int xi1 = (int)fminf(fmaxf(x0f + 1.f, 0.f), 127.f);
    float w00 = wy0 * wx0 * ((vy0 && vx0) ? 1.f : 0.f);
    float w01 = wy0 * wx1 * ((vy0 && vx1) ? 1.f : 0.f);
    float w10 = wy1 * wx0 * ((vy1 && vx0) ? 1.f : 0.f);
    float w11 = wy1 * wx1 * ((vy1 && vx1) ? 1.f : 0.f);

    const __bf16* c00 = xb + ((size_t)((yi0 + 3) * 134) + xi0 + 3) * 64;
    const __bf16* c01 = xb + ((size_t)((yi0 + 3) * 134) + xi1 + 3) * 64;
    const __bf16* c10 = xb + ((size_t)((yi1 + 3) * 134) + xi0 + 3) * 64;
    const __bf16* c11 = xb + ((size_t)((yi1 + 3) * 134) + xi1 + 3) * 64;

#pragma unroll 2
    for (int oct = 0; oct < 8; oct++) {
      bf16x8 v00 = *(const bf16x8*)(c00 + oct * 8);
      bf16x8 v01 = *(const bf16x8*)(c01 + oct * 8);
      bf16x8 v10 = *(const bf16x8*)(c10 + oct * 8);
      bf16x8 v11 = *(const bf16x8*)(c11 + oct * 8);
      bf16x8 r;
#pragma unroll
      for (int j = 0; j < 8; j++) {
        float f = w00 * (float)v00[j] + w01 * (float)v01[j]
                + w10 * (float)v10[j] + w11 * (float)v11[j];
        r[j] = (__bf16)f;
      }
      *(bf16x8*)(sm + oct * 1024 + lane * 16) = r;
    }

#pragma unroll
    for (int s = 0; s < 2; s++) {
      bf16x8 a0 = aD[((k * 2 + s) * 4 + 0) * 64 + lane];
      bf16x8 a1 = aD[((k * 2 + s) * 4 + 1) * 64 + lane];
      bf16x8 a2 = aD[((k * 2 + s) * 4 + 2) * 64 + lane];
      bf16x8 a3 = aD[((k * 2 + s) * 4 + 3) * 64 + lane];
#pragma unroll
      for (int nf = 0; nf < 4; nf++) {
        bf16x8 bv = *(const bf16x8*)(sm + (s * 4 + (lane >> 4)) * 1024
                                        + (nf * 16 + (lane & 15)) * 16);
        acc[0][nf] = __builtin_amdgcn_mfma_f32_16x16x32_bf16(a0, bv, acc[0][nf], 0, 0, 0);
        acc[1][nf] = __builtin_amdgcn_mfma_f32_16x16x32_bf16(a1, bv, acc[1][nf], 0, 0, 0);
        acc[2][nf] = __builtin_amdgcn_mfma_f32_16x16x32_bf16(a2, bv, acc[2][nf], 0, 0, 0);
        acc[3][nf] = __builtin_amdgcn_mfma_f32_16x16x32_bf16(a3, bv, acc[3][nf], 0, 0, 0);
      }
    }
  }

#pragma unroll
  for (int mf = 0; mf < 4; mf++) {
    int o = mf * 16 + ((lane >> 4) << 2);
    float b0 = dcn_b[o], b1v = dcn_b[o + 1], b2v = dcn_b[o + 2], b3v = dcn_b[o + 3];
#pragma unroll
    for (int nf = 0; nf < 4; nf++) {
      int px = half * 64 + nf * 16 + (lane & 15);
      bf16x4 r;
      r[0] = (__bf16)(acc[mf][nf][0] + b0);
      r[1] = (__bf16)(acc[mf][nf][1] + b1v);
      r[2] = (__bf16)(acc[mf][nf][2] + b2v);
      r[3] = (__bf16)(acc[mf][nf][3] + b3v);
      *(bf16x4*)(FdT + ((size_t)b * HWn + h * 128 + px) * 64 + o) = r;
    }
  }
}

// ---------------------------------------------------------------------------
// K7: fusion -> fusedT bf16 channels-last, zero-padded 2 ring [b][132][132][64].
// ---------------------------------------------------------------------------
__global__ __launch_bounds__(256) void k_fuseT(
    const __bf16* __restrict__ FsT, const __bf16* __restrict__ FdT,
    const float* __restrict__ wg_w, const float* __restrict__ wg_b,
    __bf16* __restrict__ fusedT)
{
  int id = blockIdx.x * 256 + threadIdx.x;
  if (id >= 8 * 132 * 132) return;
  int wp = id % 132;
  int hp = (id / 132) % 132;
  int b  = id / (132 * 132);
  __bf16* dst = fusedT + (size_t)id * 64;
  int h = hp - 2, w = wp - 2;
  if (((unsigned)h >= 128u) || ((unsigned)w >= 128u)) {
    bf16x8 z = {};
#pragma unroll
    for (int oct = 0; oct < 8; oct++) *(bf16x8*)(dst + oct * 8) = z;
    return;
  }
  const bf16x8* fs = (const bf16x8*)(FsT + ((size_t)b * HWn + h * 128 + w) * 64);
  const bf16x8* fd = (const bf16x8*)(FdT + ((size_t)b * HWn + h * 128 + w) * 64);
  bf16x8 fsv[8], fdv[8];
  float s0 = wg_b[0], s1 = wg_b[1];
#pragma unroll
  for (int oct = 0; oct < 8; oct++) {
    fsv[oct] = fs[oct];
    fdv[oct] = fd[oct];
#pragma unroll
    for (int j = 0; j < 8; j++) {
      int c = oct * 8 + j;
      float a = (float)fsv[oct][j], d = (float)fdv[oct][j];
      s0 = fmaf(wg_w[c],       a, fmaf(wg_w[64 + c],  d, s0));
      s1 = fmaf(wg_w[128 + c], a, fmaf(wg_w[192 + c], d, s1));
    }
  }
  float p0 = 1.f / (1.f + __expf(s1 - s0));
  float p1 = 1.f - p0;
#pragma unroll
  for (int oct = 0; oct < 8; oct++) {
    bf16x8 r;
#pragma unroll
    for (int j = 0; j < 8; j++)
      r[j] = (__bf16)(p0 * (float)fsv[oct][j] + p1 * (float)fdv[oct][j]);
    *(bf16x8*)(dst + oct * 8) = r;
  }
}

// ---------------------------------------------------------------------------
// K8: collapsed ELK via MFMA.
// ---------------------------------------------------------------------------
__global__ __launch_bounds__(256) void k_elkm(
    const __bf16* __restrict__ fusedT, const __bf16* __restrict__ weffD,
    const float* __restrict__ beff, float* __restrict__ out)
{
  const int DY[13] = {-2,-1,-1,-1, 0, 0, 0, 0, 0, 1, 1, 1, 2};
  const int DX[13] = { 0,-1, 0, 1,-2,-1, 0, 1, 2,-1, 0, 1, 0};
  const int lane = threadIdx.x & 63;
  const int wv   = threadIdx.x >> 6;
  const int b    = blockIdx.x >> 6;
  const int h    = (blockIdx.x & 63) * 2 + (wv >> 1);
  const int half = wv & 1;

  f32x4 acc[4][4];
#pragma unroll
  for (int mf = 0; mf < 4; mf++)
#pragma unroll
    for (int nf = 0; nf < 4; nf++) acc[mf][nf] = (f32x4){0.f, 0.f, 0.f, 0.f};

  const bf16x8* aD = (const bf16x8*)weffD;

  for (int t = 0; t < 13; t++) {
    int hp = h + 2 + DY[t];
    const __bf16* base = fusedT
        + ((size_t)((b * 132 + hp) * 132) + half * 64 + 2 + DX[t]) * 64;
#pragma unroll
    for (int s = 0; s < 2; s++) {
      bf16x8 a0 = aD[((t * 2 + s) * 4 + 0) * 64 + lane];
      bf16x8 a1 = aD[((t * 2 + s) * 4 + 1) * 64 + lane];
      bf16x8 a2 = aD[((t * 2 + s) * 4 + 2) * 64 + lane];
      bf16x8 a3 = aD[((t * 2 + s) * 4 + 3) * 64 + lane];
#pragma unroll
      for (int nf = 0; nf < 4; nf++) {
        bf16x8 bv = *(const bf16x8*)(base + (size_t)(nf * 16 + (lane & 15)) * 64
                                          + s * 32 + (lane >> 4) * 8);
        acc[0][nf] = __builtin_amdgcn_mfma_f32_16x16x32_bf16(a0, bv, acc[0][nf], 0, 0, 0);
        acc[1][nf] = __builtin_amdgcn_mfma_f32_16x16x32_bf16(a1, bv, acc[1][nf], 0, 0, 0);
        acc[2][nf] = __builtin_amdgcn_mfma_f32_16x16x32_bf16(a2, bv, acc[2][nf], 0, 0, 0);
        acc[3][nf] = __builtin_amdgcn_mfma_f32_16x16x32_bf16(a3, bv, acc[3][nf], 0, 0, 0);
      }
    }
  }

#pragma unroll
  for (int mf = 0; mf < 4; mf++) {
    int ob = mf * 16 + ((lane >> 4) << 2);
#pragma unroll
    for (int r = 0; r < 4; r++) {
      int o = ob + r;
      float bb = beff[o];
      float* orow = out + ((size_t)(b * 64 + o)) * HWn + h * 128 + half * 64 + (lane & 15);
#pragma unroll
      for (int nf = 0; nf < 4; nf++)
        orow[nf * 16] = acc[mf][nf][r] + bb;
    }
  }
}

// ---------------------------------------------------------------------------
// Workspace layout (FLOAT offsets; bf16 buffers sized in bytes = 2*elems).
// Fixed from R2: every buffer now has correctly-sized, lifetime-checked slots.
//   xT     [0,          4,596,736)  bf16 9,193,472 el (18.39 MB); k_xt..k_dcnm
//   fusedT [0,          4,460,544)  bf16 8,921,088 el; reuses xT (dead) after k_dcnm
//   t1     [4,596,736,  8,791,040)  f32 4,194,304;  k_conv1m..k_pool
//   FsT    [4,596,736,  8,791,040)  bf16 8,388,608 el; reuses t1 after k_feat
//   p1     [8,791,040,  9,839,616)  f32 1,048,576;  k_pool..k_conv2
//   t2     [9,839,616, 11,936,768)  f32 2,097,152;  k_conv2..k_feat
//   FdT    [8,791,040, 12,985,344)  bf16 8,388,608 el; reuses p1+t2 after k_theta
//   feat   [12,985,344, +512)  theta [12,985,856, +64)
//   wfrag  [12,985,920, +50,176)  w2T [13,036,096, +51,200)  beff [13,087,296, +64)
//   dcnD   [13,087,360, +18,432)  weffD [13,105,792, +26,624)  end 13,132,416 (52.5 MB)
// ---------------------------------------------------------------------------
extern "C" void kernel_launch(void* const* d_in, const int* in_sizes, int n_in,
                              void* d_out, int out_size, void* d_ws, size_t ws_size,
                              hipStream_t stream)
{
  (void)in_sizes; (void)n_in; (void)out_size; (void)ws_size;
  const float* x      = (const float*)d_in[0];
  const float* offset = (const float*)d_in[1];
  const float* stn_w1 = (const float*)d_in[2];
  const float* stn_b1 = (const float*)d_in[3];
  const float* stn_w2 = (const float*)d_in[4];
  const float* stn_b2 = (const float*)d_in[5];
  const float* fc_w   = (const float*)d_in[6];
  const float* fc_b   = (const float*)d_in[7];
  const float* dcn_w  = (const float*)d_in[8];
  const float* dcn_b  = (const float*)d_in[9];
  const float* wg_w   = (const float*)d_in[10];
  const float* wg_b   = (const float*)d_in[11];
  const float* w3     = (const float*)d_in[12];
  const float* b3     = (const float*)d_in[13];
  const float* w15    = (const float*)d_in[14];
  const float* b15    = (const float*)d_in[15];
  const float* w51    = (const float*)d_in[16];
  const float* b51    = (const float*)d_in[17];
  const float* w1     = (const float*)d_in[18];
  const float* b1     = (const float*)d_in[19];

  float* ws     = (float*)d_ws;
  __bf16* xT    = (__bf16*)ws;
  __bf16* fusedT= (__bf16*)ws;
  float* t1     = ws + 4596736;
  __bf16* FsT   = (__bf16*)(ws + 4596736);
  float* p1     = ws + 8791040;
  float* t2     = ws + 9839616;
  __bf16* FdT   = (__bf16*)(ws + 8791040);
  float* feat   = ws + 12985344;
  float* theta  = ws + 12985856;
  __bf16* wfrag = (__bf16*)(ws + 12985920);
  float* w2T    = ws + 13036096;
  float* beff   = ws + 13087296;
  __bf16* dcnD  = (__bf16*)(ws + 13087360);
  __bf16* weffD = (__bf16*)(ws + 13105792);
  float* out    = (float*)d_out;

  k_prep  <<<201,  256, 0, stream>>>(stn_w2, w1, b3, b15, b51, b1, w2T, beff);
  k_xt    <<<562,  256, 0, stream>>>(x, xT);
  k_wf    <<<392,  256, 0, stream>>>(stn_w1, wfrag);
  k_frag  <<<352,  256, 0, stream>>>(dcn_w, w1, w3, w15, w51, dcnD, weffD);
  k_conv1m<<<512,  128, 0, stream>>>(xT, wfrag, stn_b1, t1);
  k_pool  <<<4096, 256, 0, stream>>>(t1, p1);
  k_conv2 <<<512,  256, 0, stream>>>(p1, w2T, stn_b2, t2);
  k_feat  <<<512,  256, 0, stream>>>(t2, feat);
  k_theta <<<1,    64,  0, stream>>>(feat, fc_w, fc_b, theta);
  k_fs    <<<512,  256, 0, stream>>>(x, theta, FsT);
  k_dcnm  <<<512,  256, 0, stream>>>(xT, offset, dcnD, dcn_b, FdT);
  k_fuseT <<<545,  256, 0, stream>>>(FsT, FdT, wg_w, wg_b, fusedT);
  k_elkm  <<<512,  256, 0, stream>>>(fusedT, weffD, beff, out);
}

// Round 6
// 333.842 us; speedup vs baseline: 3.6361x; 1.3876x over previous
//
#include <hip/hip_runtime.h>
#include <math.h>

// Problem dims
#define Bn 8
#define Cn 64
#define Hn 128
#define Wn 128
#define HWn 16384

typedef __attribute__((ext_vector_type(8))) __bf16 bf16x8;
typedef __attribute__((ext_vector_type(4))) __bf16 bf16x4;
typedef __attribute__((ext_vector_type(4))) float f32x4;

// ---------------------------------------------------------------------------
// K0: beff (collapsed ELK bias) only.
// ---------------------------------------------------------------------------
__global__ void k_prep(const float* __restrict__ w1, const float* __restrict__ b3,
                       const float* __restrict__ b15, const float* __restrict__ b51,
                       const float* __restrict__ b1, float* __restrict__ beff)
{
  int e = threadIdx.x;
  if (e >= 64) return;
  float s = b1[e];
  for (int m = 0; m < 64; m++) {
    s = fmaf(w1[e * 192 + m],       b3[m],  s);
    s = fmaf(w1[e * 192 + 64 + m],  b15[m], s);
    s = fmaf(w1[e * 192 + 128 + m], b51[m], s);
  }
  beff[e] = s;
}

// ---------------------------------------------------------------------------
// K-xt: x (NCHW f32) -> xT[b][hp134][wp134][c64] bf16 (3-pad ring, for dcn/fs)
//                    -> xC[b][oct8][hp134][slot144][8ch] bf16 (conv1 staging;
//                       slots 134..143 never read by MFMA, left unwritten)
// ---------------------------------------------------------------------------
__global__ __launch_bounds__(256) void k_xt(const float* __restrict__ x,
                                            __bf16* __restrict__ xT,
                                            __bf16* __restrict__ xC)
{
  int t = blockIdx.x * 256 + threadIdx.x;
  if (t >= 8 * 134 * 134) return;
  int wp = t % 134;
  int hp = (t / 134) % 134;
  int b  = t / (134 * 134);
  int h = hp - 3, w = wp - 3;
  bool inb = ((unsigned)h < 128u) && ((unsigned)w < 128u);
  const float* xb = x + (size_t)b * Cn * HWn + h * 128 + w;
  __bf16* dst = xT + (size_t)t * 64;
#pragma unroll
  for (int oct = 0; oct < 8; oct++) {
    bf16x8 v;
#pragma unroll
    for (int j = 0; j < 8; j++)
      v[j] = inb ? (__bf16)xb[(size_t)(oct * 8 + j) * HWn] : (__bf16)0.f;
    *(bf16x8*)(dst + oct * 8) = v;
    *(bf16x8*)(xC + ((((size_t)b * 8 + oct) * 134 + hp) * 144 + wp) * 8) = v;
  }
}

// ---------------------------------------------------------------------------
// K-wf: stn_w1 -> A-fragment layout for conv1 MFMA.
// ---------------------------------------------------------------------------
__global__ __launch_bounds__(256) void k_wf(const float* __restrict__ stn_w1,
                                            __bf16* __restrict__ wfrag)
{
  int t = blockIdx.x * 256 + threadIdx.x;
  if (t >= 100352) return;
  int e   = t & 7;
  int l   = (t >> 3) & 63;
  int o16 = (t >> 9) & 1;
  int ck  = (t >> 10) & 1;
  int tap = t >> 11;
  int o = o16 * 16 + (l & 15);
  int c = ck * 32 + (l >> 4) * 8 + e;
  wfrag[t] = (__bf16)stn_w1[(o * 64 + c) * 49 + tap];
}

// ---------------------------------------------------------------------------
// K-frag: A-fragments for DCN (9 taps), collapsed ELK (13 taps), conv2 (25 taps).
// ---------------------------------------------------------------------------
__global__ __launch_bounds__(256) void k_frag(
    const float* __restrict__ dcn_w, const float* __restrict__ w1,
    const float* __restrict__ w3, const float* __restrict__ w15,
    const float* __restrict__ w51, const float* __restrict__ stn_w2,
    __bf16* __restrict__ dcnD, __bf16* __restrict__ weffD,
    __bf16* __restrict__ w2frag)
{
  int t = blockIdx.x * 256 + threadIdx.x;
  if (t < 36864) {
    int e = t & 7, l = (t >> 3) & 63, mf = (t >> 9) & 3, s = (t >> 11) & 1;
    int tap = t >> 12;
    int o = mf * 16 + (l & 15), c = s * 32 + (l >> 4) * 8 + e;
    dcnD[t] = (__bf16)dcn_w[(o * 64 + c) * 9 + tap];
    return;
  }
  t -= 36864;
  if (t < 53248) {
    const int DY[13] = {-2,-1,-1,-1, 0, 0, 0, 0, 0, 1, 1, 1, 2};
    const int DX[13] = { 0,-1, 0, 1,-2,-1, 0, 1, 2,-1, 0, 1, 0};
    int e = t & 7, l = (t >> 3) & 63, mf = (t >> 9) & 3, s = (t >> 11) & 1;
    int tap = t >> 12;
    int o = mf * 16 + (l & 15), c = s * 32 + (l >> 4) * 8 + e;
    int dy = DY[tap], dx = DX[tap];
    float v = 0.f;
    if (dy >= -1 && dy <= 1 && dx >= -1 && dx <= 1) {
      int k3 = (dy + 1) * 3 + (dx + 1);
      for (int m = 0; m < 64; m++) v = fmaf(w1[o * 192 + m], w3[(m * 64 + c) * 9 + k3], v);
    }
    if (dy == 0) {
      int k15 = dx + 2;
      for (int m = 0; m < 64; m++) v = fmaf(w1[o * 192 + 64 + m], w15[(m * 64 + c) * 5 + k15], v);
    }
    if (dx == 0) {
      int k51 = dy + 2;
      for (int m = 0; m < 64; m++) v = fmaf(w1[o * 192 + 128 + m], w51[(m * 64 + c) * 5 + k51], v);
    }
    weffD[t] = (__bf16)v;
    return;
  }
  t -= 53248;
  if (t < 51200) {   // conv2 A-frags: [tap25][mf4][lane64][e8]
    int e = t & 7, l = (t >> 3) & 63, mf = (t >> 9) & 3;
    int tap = t >> 11;
    int o = mf * 16 + (l & 15), c = (l >> 4) * 8 + e;
    w2frag[t] = (__bf16)stn_w2[(o * 32 + c) * 25 + tap];
  }
}

// ---------------------------------------------------------------------------
// K1: STN conv1 via MFMA, contiguous 1KB global_load_lds staging from xC.
// ---------------------------------------------------------------------------
__global__ __launch_bounds__(128) void k_conv1m(
    const __bf16* __restrict__ xC, const __bf16* __restrict__ wfrag,
    const float* __restrict__ b1s, __bf16* __restrict__ t1T)
{
  __shared__ alignas(16) char tile[73728];   // [q4][r8][slot144][16B]
  const int lane = threadIdx.x & 63;
  const int wv   = threadIdx.x >> 6;
  const int b    = blockIdx.x >> 6;
  const int h0   = (blockIdx.x & 63) * 2;

  f32x4 acc[2][8];
#pragma unroll
  for (int o16 = 0; o16 < 2; o16++)
#pragma unroll
    for (int nf = 0; nf < 8; nf++) acc[o16][nf] = (f32x4){0.f, 0.f, 0.f, 0.f};

  const bf16x8* wf = (const bf16x8*)wfrag;
  const char* tb = (const char*)tile;
  const char* xCb = (const char*)xC;

  for (int ck = 0; ck < 2; ck++) {
    for (int i = wv; i < 72; i += 2) {
      int q = i / 18;
      int t = i - q * 18;
      const char* src = xCb
          + (((size_t)(b * 8 + ck * 4 + q) * 134 + h0) * 2304) + t * 1024 + lane * 16;
      char* dst = (char*)tile + i * 1024;
      __builtin_amdgcn_global_load_lds(
          (const __attribute__((address_space(1))) void*)src,
          (__attribute__((address_space(3))) void*)dst, 16, 0, 0);
    }
    __syncthreads();

    for (int tap = 0; tap < 49; tap++) {
      int dy7 = tap / 7;
      int dx7 = tap - dy7 * 7;
      bf16x8 a0 = wf[((tap * 2 + ck) * 2 + 0) * 64 + lane];
      bf16x8 a1 = wf[((tap * 2 + ck) * 2 + 1) * 64 + lane];
      const char* bp = tb + (lane >> 4) * 18432 + (wv + dy7) * 2304
                          + (dx7 + (lane & 15)) * 16;
#pragma unroll
      for (int nf = 0; nf < 8; nf++) {
        bf16x8 bv = *(const bf16x8*)(bp + nf * 256);
        acc[0][nf] = __builtin_amdgcn_mfma_f32_16x16x32_bf16(a0, bv, acc[0][nf], 0, 0, 0);
        acc[1][nf] = __builtin_amdgcn_mfma_f32_16x16x32_bf16(a1, bv, acc[1][nf], 0, 0, 0);
      }
    }
    __syncthreads();
  }

  int h = h0 + wv;
#pragma unroll
  for (int o16 = 0; o16 < 2; o16++) {
    int ob = o16 * 16 + ((lane >> 4) << 2);
    float bb0 = b1s[ob], bb1 = b1s[ob + 1], bb2 = b1s[ob + 2], bb3 = b1s[ob + 3];
#pragma unroll
    for (int nf = 0; nf < 8; nf++) {
      int px = nf * 16 + (lane & 15);
      bf16x4 r;
      r[0] = (__bf16)fmaxf(acc[o16][nf][0] + bb0, 0.f);
      r[1] = (__bf16)fmaxf(acc[o16][nf][1] + bb1, 0.f);
      r[2] = (__bf16)fmaxf(acc[o16][nf][2] + bb2, 0.f);
      r[3] = (__bf16)fmaxf(acc[o16][nf][3] + bb3, 0.f);
      *(bf16x4*)(t1T + (((size_t)(b * 128 + h) * 128 + px)) * 32 + ob) = r;
    }
  }
}

// ---------------------------------------------------------------------------
// K2: maxpool 2x2 -> p1T[b][hp68][wp68][32ch] bf16, zero-padded 2 ring.
// ---------------------------------------------------------------------------
__global__ __launch_bounds__(256) void k_pool(const __bf16* __restrict__ t1T,
                                              __bf16* __restrict__ p1T)
{
  int id = blockIdx.x * 256 + threadIdx.x;
  if (id >= 8 * 68 * 68) return;
  int wp = id % 68, hp = (id / 68) % 68, b = id / (68 * 68);
  __bf16* dst = p1T + (size_t)id * 32;
  int ph = hp - 2, pw = wp - 2;
  if (((unsigned)ph >= 64u) || ((unsigned)pw >= 64u)) {
    bf16x8 z = {};
#pragma unroll
    for (int g = 0; g < 4; g++) *(bf16x8*)(dst + g * 8) = z;
    return;
  }
  const __bf16* s = t1T + (((size_t)(b * 128) + ph * 2) * 128 + pw * 2) * 32;
#pragma unroll
  for (int g = 0; g < 4; g++) {
    bf16x8 v0 = *(const bf16x8*)(s + g * 8);
    bf16x8 v1 = *(const bf16x8*)(s + 32 + g * 8);
    bf16x8 v2 = *(const bf16x8*)(s + 4096 + g * 8);
    bf16x8 v3 = *(const bf16x8*)(s + 4128 + g * 8);
    bf16x8 r;
#pragma unroll
    for (int j = 0; j < 8; j++) {
      float m = fmaxf(fmaxf((float)v0[j], (float)v1[j]),
                      fmaxf((float)v2[j], (float)v3[j]));
      r[j] = (__bf16)m;
    }
    *(bf16x8*)(dst + g * 8) = r;
  }
}

// ---------------------------------------------------------------------------
// K3: conv2 via MFMA. Block = 4 waves = 4 output rows; wave = 64px x 64 out.
// ---------------------------------------------------------------------------
__global__ __launch_bounds__(256) void k_conv2m(
    const __bf16* __restrict__ p1T, const __bf16* __restrict__ w2frag,
    const float* __restrict__ b2s, float* __restrict__ t2)
{
  __shared__ alignas(16) char tile[34816];   // 8*68*64
  const int lane = threadIdx.x & 63;
  const int wv   = threadIdx.x >> 6;
  const int b    = blockIdx.x >> 4;
  const int h0   = (blockIdx.x & 15) * 4;

  f32x4 acc[4][4];
#pragma unroll
  for (int mf = 0; mf < 4; mf++)
#pragma unroll
    for (int nf = 0; nf < 4; nf++) acc[mf][nf] = (f32x4){0.f, 0.f, 0.f, 0.f};

  const char* src0 = (const char*)p1T + (((size_t)b * 68 + h0) * 68) * 64;
  for (int i = wv; i < 34; i += 4) {
    __builtin_amdgcn_global_load_lds(
        (const __attribute__((address_space(1))) void*)(src0 + i * 1024 + lane * 16),
        (__attribute__((address_space(3))) void*)((char*)tile + i * 1024), 16, 0, 0);
  }
  __syncthreads();

  const bf16x8* wf = (const bf16x8*)w2frag;
  const char* tb = (const char*)tile;
  for (int tap = 0; tap < 25; tap++) {
    int ky = tap / 5, kx = tap - ky * 5;
    bf16x8 a0 = wf[(tap * 4 + 0) * 64 + lane];
    bf16x8 a1 = wf[(tap * 4 + 1) * 64 + lane];
    bf16x8 a2 = wf[(tap * 4 + 2) * 64 + lane];
    bf16x8 a3 = wf[(tap * 4 + 3) * 64 + lane];
    const char* bp = tb + (((wv + ky) * 68 + kx + (lane & 15)) * 64) + (lane >> 4) * 16;
#pragma unroll
    for (int nf = 0; nf < 4; nf++) {
      bf16x8 bv = *(const bf16x8*)(bp + nf * 1024);
      acc[0][nf] = __builtin_amdgcn_mfma_f32_16x16x32_bf16(a0, bv, acc[0][nf], 0, 0, 0);
      acc[1][nf] = __builtin_amdgcn_mfma_f32_16x16x32_bf16(a1, bv, acc[1][nf], 0, 0, 0);
      acc[2][nf] = __builtin_amdgcn_mfma_f32_16x16x32_bf16(a2, bv, acc[2][nf], 0, 0, 0);
      acc[3][nf] = __builtin_amdgcn_mfma_f32_16x16x32_bf16(a3, bv, acc[3][nf], 0, 0, 0);
    }
  }

  int h = h0 + wv;
#pragma unroll
  for (int mf = 0; mf < 4; mf++) {
    int ob = mf * 16 + ((lane >> 4) << 2);
#pragma unroll
    for (int r = 0; r < 4; r++) {
      float bb = b2s[ob + r];
      float* orow = t2 + ((size_t)(b * 64 + ob + r)) * 4096 + h * 64 + (lane & 15);
#pragma unroll
      for (int nf = 0; nf < 4; nf++)
        orow[nf * 16] = fmaxf(acc[mf][nf][r] + bb, 0.f);
    }
  }
}

// ---------------------------------------------------------------------------
// K3b: deterministic spatial sum -> feat[b*64+co].
// ---------------------------------------------------------------------------
__global__ __launch_bounds__(256) void k_feat(const float* __restrict__ t2, float* __restrict__ feat)
{
  __shared__ float red[256];
  int bc = blockIdx.x;
  const float* s = t2 + (size_t)bc * 4096;
  float v = 0.f;
  for (int i = threadIdx.x; i < 4096; i += 256) v += s[i];
  red[threadIdx.x] = v;
  __syncthreads();
  for (int st = 128; st > 0; st >>= 1) {
    if (threadIdx.x < st) red[threadIdx.x] += red[threadIdx.x + st];
    __syncthreads();
  }
  if (threadIdx.x == 0) feat[bc] = red[0];
}

// ---------------------------------------------------------------------------
// K4: theta
// ---------------------------------------------------------------------------
__global__ void k_theta(const float* __restrict__ feat, const float* __restrict__ fc_w,
                        const float* __restrict__ fc_b, float* __restrict__ theta)
{
  int tid = threadIdx.x;
  if (tid >= 48) return;
  int b = tid / 6, i = tid - b * 6;
  float s = 0.f;
  for (int k = 0; k < 64; k++) s = fmaf(feat[b * 64 + k], fc_w[i * 64 + k], s);
  theta[tid] = fmaf(s, 1.f / 4096.f, fc_b[i]);
}

// ---------------------------------------------------------------------------
// K5: affine grid + bilinear sample from xT (bf16, channels-last) -> FsT.
// ---------------------------------------------------------------------------
__global__ __launch_bounds__(256) void k_fs(const __bf16* __restrict__ xT,
                                            const float* __restrict__ theta,
                                            __bf16* __restrict__ FsT)
{
  int id = blockIdx.x * 256 + threadIdx.x;
  int wi = id & 127, hi = (id >> 7) & 127, b = id >> 14;
  const float* t = theta + b * 6;
  float xn = (float)(2 * wi + 1) * (1.f / 128.f) - 1.f;
  float yn = (float)(2 * hi + 1) * (1.f / 128.f) - 1.f;
  float gx = t[0] * xn + t[1] * yn + t[2];
  float gy = t[3] * xn + t[4] * yn + t[5];
  float ix = fmaf(gx, 64.f, 63.5f);
  float iy = fmaf(gy, 64.f, 63.5f);

  float y0f = floorf(iy), x0f = floorf(ix);
  float wy1 = iy - y0f, wy0 = 1.f - wy1;
  float wx1 = ix - x0f, wx0 = 1.f - wx1;
  bool vy0 = (y0f >= 0.f) && (y0f <= 127.f);
  bool vy1 = (y0f >= -1.f) && (y0f <= 126.f);
  bool vx0 = (x0f >= 0.f) && (x0f <= 127.f);
  bool vx1 = (x0f >= -1.f) && (x0f <= 126.f);
  int yi0 = (int)fminf(fmaxf(y0f, 0.f), 127.f);
  int yi1 = (int)fminf(fmaxf(y0f + 1.f, 0.f), 127.f);
  int xi0 = (int)fminf(fmaxf(x0f, 0.f), 127.f);
  int xi1 = (int)fminf(fmaxf(x0f + 1.f, 0.f), 127.f);
  float w00 = wy0 * wx0 * ((vy0 && vx0) ? 1.f : 0.f);
  float w01 = wy0 * wx1 * ((vy0 && vx1) ? 1.f : 0.f);
  float w10 = wy1 * wx0 * ((vy1 && vx0) ? 1.f : 0.f);
  float w11 = wy1 * wx1 * ((vy1 && vx1) ? 1.f : 0.f);

  const __bf16* xb = xT + (size_t)b * 134 * 134 * 64;
  const __bf16* c00 = xb + ((size_t)(yi0 + 3) * 134 + xi0 + 3) * 64;
  const __bf16* c01 = xb + ((size_t)(yi0 + 3) * 134 + xi1 + 3) * 64;
  const __bf16* c10 = xb + ((size_t)(yi1 + 3) * 134 + xi0 + 3) * 64;
  const __bf16* c11 = xb + ((size_t)(yi1 + 3) * 134 + xi1 + 3) * 64;
  __bf16* dst = FsT + ((size_t)b * HWn + hi * 128 + wi) * 64;
#pragma unroll 2
  for (int oct = 0; oct < 8; oct++) {
    bf16x8 v00 = *(const bf16x8*)(c00 + oct * 8);
    bf16x8 v01 = *(const bf16x8*)(c01 + oct * 8);
    bf16x8 v10 = *(const bf16x8*)(c10 + oct * 8);
    bf16x8 v11 = *(const bf16x8*)(c11 + oct * 8);
    bf16x8 r;
#pragma unroll
    for (int j = 0; j < 8; j++) {
      float f = w00 * (float)v00[j] + w01 * (float)v01[j]
              + w10 * (float)v10[j] + w11 * (float)v11[j];
      r[j] = (__bf16)f;
    }
    *(bf16x8*)(dst + oct * 8) = r;
  }
}

// ---------------------------------------------------------------------------
// K6: deformable conv via MFMA.
// ---------------------------------------------------------------------------
__global__ __launch_bounds__(256) void k_dcnm(
    const __bf16* __restrict__ xT, const float* __restrict__ off,
    const __bf16* __restrict__ dcnD, const float* __restrict__ dcn_b,
    __bf16* __restrict__ FdT)
{
  __shared__ alignas(16) char smem[4][8192];
  const int lane = threadIdx.x & 63;
  const int wv   = threadIdx.x >> 6;
  const int b    = blockIdx.x >> 6;
  const int h    = (blockIdx.x & 63) * 2 + (wv >> 1);
  const int half = wv & 1;
  const int w    = half * 64 + lane;

  f32x4 acc[4][4];
#pragma unroll
  for (int mf = 0; mf < 4; mf++)
#pragma unroll
    for (int nf = 0; nf < 4; nf++) acc[mf][nf] = (f32x4){0.f, 0.f, 0.f, 0.f};

  const float* ob = off + (size_t)b * 18 * HWn + h * 128 + w;
  char* sm = smem[wv];
  const bf16x8* aD = (const bf16x8*)dcnD;
  const __bf16* xb = xT + (size_t)b * 134 * 134 * 64;

  for (int k = 0; k < 9; k++) {
    float dy = ob[(size_t)(2 * k) * HWn];
    float dx = ob[(size_t)(2 * k + 1) * HWn];
    float sy = (float)(h + k / 3 - 1) + dy;
    float sx = (float)(w + (k % 3) - 1) + dx;

    float y0f = floorf(sy), x0f = floorf(sx);
    float wy1 = sy - y0f, wy0 = 1.f - wy1;
    float wx1 = sx - x0f, wx0 = 1.f - wx1;
    bool vy0 = (y0f >= 0.f) && (y0f <= 127.f);
    bool vy1 = (y0f >= -1.f) && (y0f <= 126.f);
    bool vx0 = (x0f >= 0.f) && (x0f <= 127.f);
    bool vx1 = (x0f >= -1.f) && (x0f <= 126.f);
    int yi0 = (int)fminf(fmaxf(y0f, 0.f), 127.f);
    int yi1 = (int)fminf(fmaxf(y0f + 1.f, 0.f), 127.f);
    int xi0 = (int)fminf(fmaxf(x0f, 0.f), 127.f);
    int xi1 = (int)fminf(fmaxf(x0f + 1.f, 0.f), 127.f);
    float w00 = wy0 * wx0 * ((vy0 && vx0) ? 1.f : 0.f);
    float w01 = wy0 * wx1 * ((vy0 && vx1) ? 1.f : 0.f);
    float w10 = wy1 * wx0 * ((vy1 && vx0) ? 1.f : 0.f);
    float w11 = wy1 * wx1 * ((vy1 && vx1) ? 1.f : 0.f);

    const __bf16* c00 = xb + ((size_t)((yi0 + 3) * 134) + xi0 + 3) * 64;
    const __bf16* c01 = xb + ((size_t)((yi0 + 3) * 134) + xi1 + 3) * 64;
    const __bf16* c10 = xb + ((size_t)((yi1 + 3) * 134) + xi0 + 3) * 64;
    const __bf16* c11 = xb + ((size_t)((yi1 + 3) * 134) + xi1 + 3) * 64;

#pragma unroll 2
    for (int oct = 0; oct < 8; oct++) {
      bf16x8 v00 = *(const bf16x8*)(c00 + oct * 8);
      bf16x8 v01 = *(const bf16x8*)(c01 + oct * 8);
      bf16x8 v10 = *(const bf16x8*)(c10 + oct * 8);
      bf16x8 v11 = *(const bf16x8*)(c11 + oct * 8);
      bf16x8 r;
#pragma unroll
      for (int j = 0; j < 8; j++) {
        float f = w00 * (float)v00[j] + w01 * (float)v01[j]
                + w10 * (float)v10[j] + w11 * (float)v11[j];
        r[j] = (__bf16)f;
      }
      *(bf16x8*)(sm + oct * 1024 + lane * 16) = r;
    }

#pragma unroll
    for (int s = 0; s < 2; s++) {
      bf16x8 a0 = aD[((k * 2 + s) * 4 + 0) * 64 + lane];
      bf16x8 a1 = aD[((k * 2 + s) * 4 + 1) * 64 + lane];
      bf16x8 a2 = aD[((k * 2 + s) * 4 + 2) * 64 + lane];
      bf16x8 a3 = aD[((k * 2 + s) * 4 + 3) * 64 + lane];
#pragma unroll
      for (int nf = 0; nf < 4; nf++) {
        bf16x8 bv = *(const bf16x8*)(sm + (s * 4 + (lane >> 4)) * 1024
                                        + (nf * 16 + (lane & 15)) * 16);
        acc[0][nf] = __builtin_amdgcn_mfma_f32_16x16x32_bf16(a0, bv, acc[0][nf], 0, 0, 0);
        acc[1][nf] = __builtin_amdgcn_mfma_f32_16x16x32_bf16(a1, bv, acc[1][nf], 0, 0, 0);
        acc[2][nf] = __builtin_amdgcn_mfma_f32_16x16x32_bf16(a2, bv, acc[2][nf], 0, 0, 0);
        acc[3][nf] = __builtin_amdgcn_mfma_f32_16x16x32_bf16(a3, bv, acc[3][nf], 0, 0, 0);
      }
    }
  }

#pragma unroll
  for (int mf = 0; mf < 4; mf++) {
    int o = mf * 16 + ((lane >> 4) << 2);
    float b0 = dcn_b[o], b1v = dcn_b[o + 1], b2v = dcn_b[o + 2], b3v = dcn_b[o + 3];
#pragma unroll
    for (int nf = 0; nf < 4; nf++) {
      int px = half * 64 + nf * 16 + (lane & 15);
      bf16x4 r;
      r[0] = (__bf16)(acc[mf][nf][0] + b0);
      r[1] = (__bf16)(acc[mf][nf][1] + b1v);
      r[2] = (__bf16)(acc[mf][nf][2] + b2v);
      r[3] = (__bf16)(acc[mf][nf][3] + b3v);
      *(bf16x4*)(FdT + ((size_t)b * HWn + h * 128 + px) * 64 + o) = r;
    }
  }
}

// ---------------------------------------------------------------------------
// K7: fusion -> fusedT bf16 channels-last, zero-padded 2 ring [b][132][132][64].
// ---------------------------------------------------------------------------
__global__ __launch_bounds__(256) void k_fuseT(
    const __bf16* __restrict__ FsT, const __bf16* __restrict__ FdT,
    const float* __restrict__ wg_w, const float* __restrict__ wg_b,
    __bf16* __restrict__ fusedT)
{
  int id = blockIdx.x * 256 + threadIdx.x;
  if (id >= 8 * 132 * 132) return;
  int wp = id % 132;
  int hp = (id / 132) % 132;
  int b  = id / (132 * 132);
  __bf16* dst = fusedT + (size_t)id * 64;
  int h = hp - 2, w = wp - 2;
  if (((unsigned)h >= 128u) || ((unsigned)w >= 128u)) {
    bf16x8 z = {};
#pragma unroll
    for (int oct = 0; oct < 8; oct++) *(bf16x8*)(dst + oct * 8) = z;
    return;
  }
  const bf16x8* fs = (const bf16x8*)(FsT + ((size_t)b * HWn + h * 128 + w) * 64);
  const bf16x8* fd = (const bf16x8*)(FdT + ((size_t)b * HWn + h * 128 + w) * 64);
  bf16x8 fsv[8], fdv[8];
  float s0 = wg_b[0], s1 = wg_b[1];
#pragma unroll
  for (int oct = 0; oct < 8; oct++) {
    fsv[oct] = fs[oct];
    fdv[oct] = fd[oct];
#pragma unroll
    for (int j = 0; j < 8; j++) {
      int c = oct * 8 + j;
      float a = (float)fsv[oct][j], d = (float)fdv[oct][j];
      s0 = fmaf(wg_w[c],       a, fmaf(wg_w[64 + c],  d, s0));
      s1 = fmaf(wg_w[128 + c], a, fmaf(wg_w[192 + c], d, s1));
    }
  }
  float p0 = 1.f / (1.f + __expf(s1 - s0));
  float p1 = 1.f - p0;
#pragma unroll
  for (int oct = 0; oct < 8; oct++) {
    bf16x8 r;
#pragma unroll
    for (int j = 0; j < 8; j++)
      r[j] = (__bf16)(p0 * (float)fsv[oct][j] + p1 * (float)fdv[oct][j]);
    *(bf16x8*)(dst + oct * 8) = r;
  }
}

// ---------------------------------------------------------------------------
// K8: collapsed ELK via MFMA.
// ---------------------------------------------------------------------------
__global__ __launch_bounds__(256) void k_elkm(
    const __bf16* __restrict__ fusedT, const __bf16* __restrict__ weffD,
    const float* __restrict__ beff, float* __restrict__ out)
{
  const int DY[13] = {-2,-1,-1,-1, 0, 0, 0, 0, 0, 1, 1, 1, 2};
  const int DX[13] = { 0,-1, 0, 1,-2,-1, 0, 1, 2,-1, 0, 1, 0};
  const int lane = threadIdx.x & 63;
  const int wv   = threadIdx.x >> 6;
  const int b    = blockIdx.x >> 6;
  const int h    = (blockIdx.x & 63) * 2 + (wv >> 1);
  const int half = wv & 1;

  f32x4 acc[4][4];
#pragma unroll
  for (int mf = 0; mf < 4; mf++)
#pragma unroll
    for (int nf = 0; nf < 4; nf++) acc[mf][nf] = (f32x4){0.f, 0.f, 0.f, 0.f};

  const bf16x8* aD = (const bf16x8*)weffD;

  for (int t = 0; t < 13; t++) {
    int hp = h + 2 + DY[t];
    const __bf16* base = fusedT
        + ((size_t)((b * 132 + hp) * 132) + half * 64 + 2 + DX[t]) * 64;
#pragma unroll
    for (int s = 0; s < 2; s++) {
      bf16x8 a0 = aD[((t * 2 + s) * 4 + 0) * 64 + lane];
      bf16x8 a1 = aD[((t * 2 + s) * 4 + 1) * 64 + lane];
      bf16x8 a2 = aD[((t * 2 + s) * 4 + 2) * 64 + lane];
      bf16x8 a3 = aD[((t * 2 + s) * 4 + 3) * 64 + lane];
#pragma unroll
      for (int nf = 0; nf < 4; nf++) {
        bf16x8 bv = *(const bf16x8*)(base + (size_t)(nf * 16 + (lane & 15)) * 64
                                          + s * 32 + (lane >> 4) * 8);
        acc[0][nf] = __builtin_amdgcn_mfma_f32_16x16x32_bf16(a0, bv, acc[0][nf], 0, 0, 0);
        acc[1][nf] = __builtin_amdgcn_mfma_f32_16x16x32_bf16(a1, bv, acc[1][nf], 0, 0, 0);
        acc[2][nf] = __builtin_amdgcn_mfma_f32_16x16x32_bf16(a2, bv, acc[2][nf], 0, 0, 0);
        acc[3][nf] = __builtin_amdgcn_mfma_f32_16x16x32_bf16(a3, bv, acc[3][nf], 0, 0, 0);
      }
    }
  }

#pragma unroll
  for (int mf = 0; mf < 4; mf++) {
    int ob = mf * 16 + ((lane >> 4) << 2);
#pragma unroll
    for (int r = 0; r < 4; r++) {
      int o = ob + r;
      float bb = beff[o];
      float* orow = out + ((size_t)(b * 64 + o)) * HWn + h * 128 + half * 64 + (lane & 15);
#pragma unroll
      for (int nf = 0; nf < 4; nf++)
        orow[nf * 16] = acc[mf][nf][r] + bb;
    }
  }
}

// ---------------------------------------------------------------------------
// Workspace layout, FLOAT offsets, sizes VERIFIED in floats (= bf16_elems/2):
// Region A [0,          4,596,736): xT (4,596,736 fl); fusedT (4,460,544 fl)
//          written by k_fuseT after xT's last read (k_dcnm). OK.
// Region B [4,596,736,  9,536,512): xC (4,939,776 fl); FsT (4,194,304 fl)
//          written by k_fs after xC's last read (k_conv1m). OK.
// Region C [9,536,512, 14,322,688): t1T (2,097,152 fl) @9,536,512;
//          p1T (591,872 fl) @11,633,664; t2 (2,097,152 fl) @12,225,536;
//          FdT (4,194,304 fl) @9,536,512 written by k_dcnm after t2's last
//          read (k_feat). OK.
// Tail:    feat @14,322,688 (512); theta @14,323,200 (64);
//          wfrag @14,323,264 (50,176); w2frag @14,373,440 (25,600);
//          beff @14,399,040 (64); dcnD @14,399,104 (18,432);
//          weffD @14,417,536 (26,624). End 14,444,160 fl = 57.8 MB.
// ---------------------------------------------------------------------------
extern "C" void kernel_launch(void* const* d_in, const int* in_sizes, int n_in,
                              void* d_out, int out_size, void* d_ws, size_t ws_size,
                              hipStream_t stream)
{
  (void)in_sizes; (void)n_in; (void)out_size; (void)ws_size;
  const float* x      = (const float*)d_in[0];
  const float* offset = (const float*)d_in[1];
  const float* stn_w1 = (const float*)d_in[2];
  const float* stn_b1 = (const float*)d_in[3];
  const float* stn_w2 = (const float*)d_in[4];
  const float* stn_b2 = (const float*)d_in[5];
  const float* fc_w   = (const float*)d_in[6];
  const float* fc_b   = (const float*)d_in[7];
  const float* dcn_w  = (const float*)d_in[8];
  const float* dcn_b  = (const float*)d_in[9];
  const float* wg_w   = (const float*)d_in[10];
  const float* wg_b   = (const float*)d_in[11];
  const float* w3     = (const float*)d_in[12];
  const float* b3     = (const float*)d_in[13];
  const float* w15    = (const float*)d_in[14];
  const float* b15    = (const float*)d_in[15];
  const float* w51    = (const float*)d_in[16];
  const float* b51    = (const float*)d_in[17];
  const float* w1     = (const float*)d_in[18];
  const float* b1     = (const float*)d_in[19];

  float* ws      = (float*)d_ws;
  __bf16* xT     = (__bf16*)ws;
  __bf16* fusedT = (__bf16*)ws;
  __bf16* xC     = (__bf16*)(ws + 4596736);
  __bf16* FsT    = (__bf16*)(ws + 4596736);
  __bf16* t1T    = (__bf16*)(ws + 9536512);
  __bf16* FdT    = (__bf16*)(ws + 9536512);
  __bf16* p1T    = (__bf16*)(ws + 11633664);
  float*  t2     = ws + 12225536;
  float*  feat   = ws + 14322688;
  float*  theta  = ws + 14323200;
  __bf16* wfrag  = (__bf16*)(ws + 14323264);
  __bf16* w2frag = (__bf16*)(ws + 14373440);
  float*  beff   = ws + 14399040;
  __bf16* dcnD   = (__bf16*)(ws + 14399104);
  __bf16* weffD  = (__bf16*)(ws + 14417536);
  float*  out    = (float*)d_out;

  k_prep  <<<1,    64,  0, stream>>>(w1, b3, b15, b51, b1, beff);
  k_xt    <<<562,  256, 0, stream>>>(x, xT, xC);
  k_wf    <<<392,  256, 0, stream>>>(stn_w1, wfrag);
  k_frag  <<<552,  256, 0, stream>>>(dcn_w, w1, w3, w15, w51, stn_w2, dcnD, weffD, w2frag);
  k_conv1m<<<512,  128, 0, stream>>>(xC, wfrag, stn_b1, t1T);
  k_pool  <<<145,  256, 0, stream>>>(t1T, p1T);
  k_conv2m<<<128,  256, 0, stream>>>(p1T, w2frag, stn_b2, t2);
  k_feat  <<<512,  256, 0, stream>>>(t2, feat);
  k_theta <<<1,    64,  0, stream>>>(feat, fc_w, fc_b, theta);
  k_fs    <<<512,  256, 0, stream>>>(xT, theta, FsT);
  k_dcnm  <<<512,  256, 0, stream>>>(xT, offset, dcnD, dcn_b, FdT);
  k_fuseT <<<545,  256, 0, stream>>>(FsT, FdT, wg_w, wg_b, fusedT);
  k_elkm  <<<512,  256, 0, stream>>>(fusedT, weffD, beff, out);
}

// Round 7
// 285.528 us; speedup vs baseline: 4.2513x; 1.1692x over previous
//
#include <hip/hip_runtime.h>
#include <math.h>

// Problem dims
#define Bn 8
#define Cn 64
#define Hn 128
#define Wn 128
#define HWn 16384

typedef __attribute__((ext_vector_type(8))) __bf16 bf16x8;
typedef __attribute__((ext_vector_type(4))) __bf16 bf16x4;
typedef __attribute__((ext_vector_type(4))) float f32x4;

// XCD-aware bijective swizzle: grid = 8*chunk blocks; XCD k (bid%8) gets the
// contiguous work range [k*chunk,(k+1)*chunk) => per-XCD L2-resident slice.
__device__ __forceinline__ int xcd_swz(int bid, int chunk) {
  return (bid & 7) * chunk + (bid >> 3);
}

// ---------------------------------------------------------------------------
// K0: beff (collapsed ELK bias) only.
// ---------------------------------------------------------------------------
__global__ void k_prep(const float* __restrict__ w1, const float* __restrict__ b3,
                       const float* __restrict__ b15, const float* __restrict__ b51,
                       const float* __restrict__ b1, float* __restrict__ beff)
{
  int e = threadIdx.x;
  if (e >= 64) return;
  float s = b1[e];
  for (int m = 0; m < 64; m++) {
    s = fmaf(w1[e * 192 + m],       b3[m],  s);
    s = fmaf(w1[e * 192 + 64 + m],  b15[m], s);
    s = fmaf(w1[e * 192 + 128 + m], b51[m], s);
  }
  beff[e] = s;
}

// ---------------------------------------------------------------------------
// K-xt: x (NCHW f32) -> xT[b][hp134][wp134][c64] bf16 (3-pad ring)
//                    -> xC[b][oct8][hp134][slot144][8ch] bf16 (conv1 staging)
// ---------------------------------------------------------------------------
__global__ __launch_bounds__(256) void k_xt(const float* __restrict__ x,
                                            __bf16* __restrict__ xT,
                                            __bf16* __restrict__ xC)
{
  int t = blockIdx.x * 256 + threadIdx.x;
  if (t >= 8 * 134 * 134) return;
  int wp = t % 134;
  int hp = (t / 134) % 134;
  int b  = t / (134 * 134);
  int h = hp - 3, w = wp - 3;
  bool inb = ((unsigned)h < 128u) && ((unsigned)w < 128u);
  const float* xb = x + (size_t)b * Cn * HWn + h * 128 + w;
  __bf16* dst = xT + (size_t)t * 64;
#pragma unroll
  for (int oct = 0; oct < 8; oct++) {
    bf16x8 v;
#pragma unroll
    for (int j = 0; j < 8; j++)
      v[j] = inb ? (__bf16)xb[(size_t)(oct * 8 + j) * HWn] : (__bf16)0.f;
    *(bf16x8*)(dst + oct * 8) = v;
    *(bf16x8*)(xC + ((((size_t)b * 8 + oct) * 134 + hp) * 144 + wp) * 8) = v;
  }
}

// ---------------------------------------------------------------------------
// K-wf: stn_w1 -> A-fragment layout for conv1 MFMA.
// ---------------------------------------------------------------------------
__global__ __launch_bounds__(256) void k_wf(const float* __restrict__ stn_w1,
                                            __bf16* __restrict__ wfrag)
{
  int t = blockIdx.x * 256 + threadIdx.x;
  if (t >= 100352) return;
  int e   = t & 7;
  int l   = (t >> 3) & 63;
  int o16 = (t >> 9) & 1;
  int ck  = (t >> 10) & 1;
  int tap = t >> 11;
  int o = o16 * 16 + (l & 15);
  int c = ck * 32 + (l >> 4) * 8 + e;
  wfrag[t] = (__bf16)stn_w1[(o * 64 + c) * 49 + tap];
}

// ---------------------------------------------------------------------------
// K-frag: A-fragments for DCN (9 taps), collapsed ELK (13 taps), conv2 (25 taps).
// ---------------------------------------------------------------------------
__global__ __launch_bounds__(256) void k_frag(
    const float* __restrict__ dcn_w, const float* __restrict__ w1,
    const float* __restrict__ w3, const float* __restrict__ w15,
    const float* __restrict__ w51, const float* __restrict__ stn_w2,
    __bf16* __restrict__ dcnD, __bf16* __restrict__ weffD,
    __bf16* __restrict__ w2frag)
{
  int t = blockIdx.x * 256 + threadIdx.x;
  if (t < 36864) {
    int e = t & 7, l = (t >> 3) & 63, mf = (t >> 9) & 3, s = (t >> 11) & 1;
    int tap = t >> 12;
    int o = mf * 16 + (l & 15), c = s * 32 + (l >> 4) * 8 + e;
    dcnD[t] = (__bf16)dcn_w[(o * 64 + c) * 9 + tap];
    return;
  }
  t -= 36864;
  if (t < 53248) {
    const int DY[13] = {-2,-1,-1,-1, 0, 0, 0, 0, 0, 1, 1, 1, 2};
    const int DX[13] = { 0,-1, 0, 1,-2,-1, 0, 1, 2,-1, 0, 1, 0};
    int e = t & 7, l = (t >> 3) & 63, mf = (t >> 9) & 3, s = (t >> 11) & 1;
    int tap = t >> 12;
    int o = mf * 16 + (l & 15), c = s * 32 + (l >> 4) * 8 + e;
    int dy = DY[tap], dx = DX[tap];
    float v = 0.f;
    if (dy >= -1 && dy <= 1 && dx >= -1 && dx <= 1) {
      int k3 = (dy + 1) * 3 + (dx + 1);
      for (int m = 0; m < 64; m++) v = fmaf(w1[o * 192 + m], w3[(m * 64 + c) * 9 + k3], v);
    }
    if (dy == 0) {
      int k15 = dx + 2;
      for (int m = 0; m < 64; m++) v = fmaf(w1[o * 192 + 64 + m], w15[(m * 64 + c) * 5 + k15], v);
    }
    if (dx == 0) {
      int k51 = dy + 2;
      for (int m = 0; m < 64; m++) v = fmaf(w1[o * 192 + 128 + m], w51[(m * 64 + c) * 5 + k51], v);
    }
    weffD[t] = (__bf16)v;
    return;
  }
  t -= 53248;
  if (t < 51200) {   // conv2 A-frags: [tap25][mf4][lane64][e8]
    int e = t & 7, l = (t >> 3) & 63, mf = (t >> 9) & 3;
    int tap = t >> 11;
    int o = mf * 16 + (l & 15), c = (l >> 4) * 8 + e;
    w2frag[t] = (__bf16)stn_w2[(o * 32 + c) * 25 + tap];
  }
}

// ---------------------------------------------------------------------------
// K1: STN conv1 via MFMA, contiguous 1KB global_load_lds staging from xC.
// XCD swizzle: chunk 64 => XCD k handles batch k (xC slice L2-resident).
// ---------------------------------------------------------------------------
__global__ __launch_bounds__(128) void k_conv1m(
    const __bf16* __restrict__ xC, const __bf16* __restrict__ wfrag,
    const float* __restrict__ b1s, __bf16* __restrict__ t1T)
{
  __shared__ alignas(16) char tile[73728];   // [q4][r8][slot144][16B]
  const int lane = threadIdx.x & 63;
  const int wv   = threadIdx.x >> 6;
  const int swz  = xcd_swz(blockIdx.x, 64);
  const int b    = swz >> 6;
  const int h0   = (swz & 63) * 2;

  f32x4 acc[2][8];
#pragma unroll
  for (int o16 = 0; o16 < 2; o16++)
#pragma unroll
    for (int nf = 0; nf < 8; nf++) acc[o16][nf] = (f32x4){0.f, 0.f, 0.f, 0.f};

  const bf16x8* wf = (const bf16x8*)wfrag;
  const char* tb = (const char*)tile;
  const char* xCb = (const char*)xC;

  for (int ck = 0; ck < 2; ck++) {
    for (int i = wv; i < 72; i += 2) {
      int q = i / 18;
      int t = i - q * 18;
      const char* src = xCb
          + (((size_t)(b * 8 + ck * 4 + q) * 134 + h0) * 2304) + t * 1024 + lane * 16;
      char* dst = (char*)tile + i * 1024;
      __builtin_amdgcn_global_load_lds(
          (const __attribute__((address_space(1))) void*)src,
          (__attribute__((address_space(3))) void*)dst, 16, 0, 0);
    }
    __syncthreads();

    for (int tap = 0; tap < 49; tap++) {
      int dy7 = tap / 7;
      int dx7 = tap - dy7 * 7;
      bf16x8 a0 = wf[((tap * 2 + ck) * 2 + 0) * 64 + lane];
      bf16x8 a1 = wf[((tap * 2 + ck) * 2 + 1) * 64 + lane];
      const char* bp = tb + (lane >> 4) * 18432 + (wv + dy7) * 2304
                          + (dx7 + (lane & 15)) * 16;
#pragma unroll
      for (int nf = 0; nf < 8; nf++) {
        bf16x8 bv = *(const bf16x8*)(bp + nf * 256);
        acc[0][nf] = __builtin_amdgcn_mfma_f32_16x16x32_bf16(a0, bv, acc[0][nf], 0, 0, 0);
        acc[1][nf] = __builtin_amdgcn_mfma_f32_16x16x32_bf16(a1, bv, acc[1][nf], 0, 0, 0);
      }
    }
    __syncthreads();
  }

  int h = h0 + wv;
#pragma unroll
  for (int o16 = 0; o16 < 2; o16++) {
    int ob = o16 * 16 + ((lane >> 4) << 2);
    float bb0 = b1s[ob], bb1 = b1s[ob + 1], bb2 = b1s[ob + 2], bb3 = b1s[ob + 3];
#pragma unroll
    for (int nf = 0; nf < 8; nf++) {
      int px = nf * 16 + (lane & 15);
      bf16x4 r;
      r[0] = (__bf16)fmaxf(acc[o16][nf][0] + bb0, 0.f);
      r[1] = (__bf16)fmaxf(acc[o16][nf][1] + bb1, 0.f);
      r[2] = (__bf16)fmaxf(acc[o16][nf][2] + bb2, 0.f);
      r[3] = (__bf16)fmaxf(acc[o16][nf][3] + bb3, 0.f);
      *(bf16x4*)(t1T + (((size_t)(b * 128 + h) * 128 + px)) * 32 + ob) = r;
    }
  }
}

// ---------------------------------------------------------------------------
// K2: maxpool 2x2 -> p1T[b][hp68][wp68][32ch] bf16, zero-padded 2 ring.
// ---------------------------------------------------------------------------
__global__ __launch_bounds__(256) void k_pool(const __bf16* __restrict__ t1T,
                                              __bf16* __restrict__ p1T)
{
  int id = blockIdx.x * 256 + threadIdx.x;
  if (id >= 8 * 68 * 68) return;
  int wp = id % 68, hp = (id / 68) % 68, b = id / (68 * 68);
  __bf16* dst = p1T + (size_t)id * 32;
  int ph = hp - 2, pw = wp - 2;
  if (((unsigned)ph >= 64u) || ((unsigned)pw >= 64u)) {
    bf16x8 z = {};
#pragma unroll
    for (int g = 0; g < 4; g++) *(bf16x8*)(dst + g * 8) = z;
    return;
  }
  const __bf16* s = t1T + (((size_t)(b * 128) + ph * 2) * 128 + pw * 2) * 32;
#pragma unroll
  for (int g = 0; g < 4; g++) {
    bf16x8 v0 = *(const bf16x8*)(s + g * 8);
    bf16x8 v1 = *(const bf16x8*)(s + 32 + g * 8);
    bf16x8 v2 = *(const bf16x8*)(s + 4096 + g * 8);
    bf16x8 v3 = *(const bf16x8*)(s + 4128 + g * 8);
    bf16x8 r;
#pragma unroll
    for (int j = 0; j < 8; j++) {
      float m = fmaxf(fmaxf((float)v0[j], (float)v1[j]),
                      fmaxf((float)v2[j], (float)v3[j]));
      r[j] = (__bf16)m;
    }
    *(bf16x8*)(dst + g * 8) = r;
  }
}

// ---------------------------------------------------------------------------
// K3: conv2 via MFMA.
// ---------------------------------------------------------------------------
__global__ __launch_bounds__(256) void k_conv2m(
    const __bf16* __restrict__ p1T, const __bf16* __restrict__ w2frag,
    const float* __restrict__ b2s, float* __restrict__ t2)
{
  __shared__ alignas(16) char tile[34816];   // 8*68*64
  const int lane = threadIdx.x & 63;
  const int wv   = threadIdx.x >> 6;
  const int b    = blockIdx.x >> 4;
  const int h0   = (blockIdx.x & 15) * 4;

  f32x4 acc[4][4];
#pragma unroll
  for (int mf = 0; mf < 4; mf++)
#pragma unroll
    for (int nf = 0; nf < 4; nf++) acc[mf][nf] = (f32x4){0.f, 0.f, 0.f, 0.f};

  const char* src0 = (const char*)p1T + (((size_t)b * 68 + h0) * 68) * 64;
  for (int i = wv; i < 34; i += 4) {
    __builtin_amdgcn_global_load_lds(
        (const __attribute__((address_space(1))) void*)(src0 + i * 1024 + lane * 16),
        (__attribute__((address_space(3))) void*)((char*)tile + i * 1024), 16, 0, 0);
  }
  __syncthreads();

  const bf16x8* wf = (const bf16x8*)w2frag;
  const char* tb = (const char*)tile;
  for (int tap = 0; tap < 25; tap++) {
    int ky = tap / 5, kx = tap - ky * 5;
    bf16x8 a0 = wf[(tap * 4 + 0) * 64 + lane];
    bf16x8 a1 = wf[(tap * 4 + 1) * 64 + lane];
    bf16x8 a2 = wf[(tap * 4 + 2) * 64 + lane];
    bf16x8 a3 = wf[(tap * 4 + 3) * 64 + lane];
    const char* bp = tb + (((wv + ky) * 68 + kx + (lane & 15)) * 64) + (lane >> 4) * 16;
#pragma unroll
    for (int nf = 0; nf < 4; nf++) {
      bf16x8 bv = *(const bf16x8*)(bp + nf * 1024);
      acc[0][nf] = __builtin_amdgcn_mfma_f32_16x16x32_bf16(a0, bv, acc[0][nf], 0, 0, 0);
      acc[1][nf] = __builtin_amdgcn_mfma_f32_16x16x32_bf16(a1, bv, acc[1][nf], 0, 0, 0);
      acc[2][nf] = __builtin_amdgcn_mfma_f32_16x16x32_bf16(a2, bv, acc[2][nf], 0, 0, 0);
      acc[3][nf] = __builtin_amdgcn_mfma_f32_16x16x32_bf16(a3, bv, acc[3][nf], 0, 0, 0);
    }
  }

  int h = h0 + wv;
#pragma unroll
  for (int mf = 0; mf < 4; mf++) {
    int ob = mf * 16 + ((lane >> 4) << 2);
#pragma unroll
    for (int r = 0; r < 4; r++) {
      float bb = b2s[ob + r];
      float* orow = t2 + ((size_t)(b * 64 + ob + r)) * 4096 + h * 64 + (lane & 15);
#pragma unroll
      for (int nf = 0; nf < 4; nf++)
        orow[nf * 16] = fmaxf(acc[mf][nf][r] + bb, 0.f);
    }
  }
}

// ---------------------------------------------------------------------------
// K3b: deterministic spatial sum -> feat[b*64+co].
// ---------------------------------------------------------------------------
__global__ __launch_bounds__(256) void k_feat(const float* __restrict__ t2, float* __restrict__ feat)
{
  __shared__ float red[256];
  int bc = blockIdx.x;
  const float* s = t2 + (size_t)bc * 4096;
  float v = 0.f;
  for (int i = threadIdx.x; i < 4096; i += 256) v += s[i];
  red[threadIdx.x] = v;
  __syncthreads();
  for (int st = 128; st > 0; st >>= 1) {
    if (threadIdx.x < st) red[threadIdx.x] += red[threadIdx.x + st];
    __syncthreads();
  }
  if (threadIdx.x == 0) feat[bc] = red[0];
}

// ---------------------------------------------------------------------------
// K4: theta
// ---------------------------------------------------------------------------
__global__ void k_theta(const float* __restrict__ feat, const float* __restrict__ fc_w,
                        const float* __restrict__ fc_b, float* __restrict__ theta)
{
  int tid = threadIdx.x;
  if (tid >= 48) return;
  int b = tid / 6, i = tid - b * 6;
  float s = 0.f;
  for (int k = 0; k < 64; k++) s = fmaf(feat[b * 64 + k], fc_w[i * 64 + k], s);
  theta[tid] = fmaf(s, 1.f / 4096.f, fc_b[i]);
}

// ---------------------------------------------------------------------------
// K5: affine grid + bilinear sample from xT -> FsT. XCD swizzle chunk 64.
// ---------------------------------------------------------------------------
__global__ __launch_bounds__(256) void k_fs(const __bf16* __restrict__ xT,
                                            const float* __restrict__ theta,
                                            __bf16* __restrict__ FsT)
{
  int id = xcd_swz(blockIdx.x, 64) * 256 + threadIdx.x;
  int wi = id & 127, hi = (id >> 7) & 127, b = id >> 14;
  const float* t = theta + b * 6;
  float xn = (float)(2 * wi + 1) * (1.f / 128.f) - 1.f;
  float yn = (float)(2 * hi + 1) * (1.f / 128.f) - 1.f;
  float gx = t[0] * xn + t[1] * yn + t[2];
  float gy = t[3] * xn + t[4] * yn + t[5];
  float ix = fmaf(gx, 64.f, 63.5f);
  float iy = fmaf(gy, 64.f, 63.5f);

  float y0f = floorf(iy), x0f = floorf(ix);
  float wy1 = iy - y0f, wy0 = 1.f - wy1;
  float wx1 = ix - x0f, wx0 = 1.f - wx1;
  bool vy0 = (y0f >= 0.f) && (y0f <= 127.f);
  bool vy1 = (y0f >= -1.f) && (y0f <= 126.f);
  bool vx0 = (x0f >= 0.f) && (x0f <= 127.f);
  bool vx1 = (x0f >= -1.f) && (x0f <= 126.f);
  int yi0 = (int)fminf(fmaxf(y0f, 0.f), 127.f);
  int yi1 = (int)fminf(fmaxf(y0f + 1.f, 0.f), 127.f);
  int xi0 = (int)fminf(fmaxf(x0f, 0.f), 127.f);
  int xi1 = (int)fminf(fmaxf(x0f + 1.f, 0.f), 127.f);
  float w00 = wy0 * wx0 * ((vy0 && vx0) ? 1.f : 0.f);
  float w01 = wy0 * wx1 * ((vy0 && vx1) ? 1.f : 0.f);
  float w10 = wy1 * wx0 * ((vy1 && vx0) ? 1.f : 0.f);
  float w11 = wy1 * wx1 * ((vy1 && vx1) ? 1.f : 0.f);

  const __bf16* xb = xT + (size_t)b * 134 * 134 * 64;
  const __bf16* c00 = xb + ((size_t)(yi0 + 3) * 134 + xi0 + 3) * 64;
  const __bf16* c01 = xb + ((size_t)(yi0 + 3) * 134 + xi1 + 3) * 64;
  const __bf16* c10 = xb + ((size_t)(yi1 + 3) * 134 + xi0 + 3) * 64;
  const __bf16* c11 = xb + ((size_t)(yi1 + 3) * 134 + xi1 + 3) * 64;
  __bf16* dst = FsT + ((size_t)b * HWn + hi * 128 + wi) * 64;
#pragma unroll 2
  for (int oct = 0; oct < 8; oct++) {
    bf16x8 v00 = *(const bf16x8*)(c00 + oct * 8);
    bf16x8 v01 = *(const bf16x8*)(c01 + oct * 8);
    bf16x8 v10 = *(const bf16x8*)(c10 + oct * 8);
    bf16x8 v11 = *(const bf16x8*)(c11 + oct * 8);
    bf16x8 r;
#pragma unroll
    for (int j = 0; j < 8; j++) {
      float f = w00 * (float)v00[j] + w01 * (float)v01[j]
              + w10 * (float)v10[j] + w11 * (float)v11[j];
      r[j] = (__bf16)f;
    }
    *(bf16x8*)(dst + oct * 8) = r;
  }
}

// ---------------------------------------------------------------------------
// K6: deformable conv via MFMA — R6 restructure.
// Wave = 32 px x 64 out (was 64 px): lane = pixel (lane&31) + octet-half
// (lane>>5). 1024 blocks x 4 waves = 4096 waves (16/CU, was 8/CU).
// XCD swizzle chunk 128 => XCD k handles batch k: 2.3MB xT slice L2-resident.
// Same-wave LDS produce/consume (no barrier needed, wave-lockstep).
// ---------------------------------------------------------------------------
__global__ __launch_bounds__(256) void k_dcnm(
    const __bf16* __restrict__ xT, const float* __restrict__ off,
    const __bf16* __restrict__ dcnD, const float* __restrict__ dcn_b,
    __bf16* __restrict__ FdT)
{
  __shared__ alignas(16) char smem[4][4096];
  const int lane = threadIdx.x & 63;
  const int wv   = threadIdx.x >> 6;
  const int swz  = xcd_swz(blockIdx.x, 128);
  const int b    = swz >> 7;
  const int h    = swz & 127;
  const int q    = wv;                 // row quarter: pixels q*32..q*32+31
  const int p    = lane & 31;
  const int og   = lane >> 5;          // octet half: 0 -> oct 0..3, 1 -> 4..7
  const int w    = q * 32 + p;

  f32x4 acc[4][2];
#pragma unroll
  for (int mf = 0; mf < 4; mf++)
#pragma unroll
    for (int nf = 0; nf < 2; nf++) acc[mf][nf] = (f32x4){0.f, 0.f, 0.f, 0.f};

  const float* ob = off + (size_t)b * 18 * HWn + h * 128 + w;
  char* sm = smem[wv];
  const bf16x8* aD = (const bf16x8*)dcnD;
  const __bf16* xb = xT + (size_t)b * 134 * 134 * 64;

  for (int k = 0; k < 9; k++) {
    float dy = ob[(size_t)(2 * k) * HWn];
    float dx = ob[(size_t)(2 * k + 1) * HWn];
    float sy = (float)(h + k / 3 - 1) + dy;
    float sx = (float)(w + (k % 3) - 1) + dx;

    float y0f = floorf(sy), x0f = floorf(sx);
    float wy1 = sy - y0f, wy0 = 1.f - wy1;
    float wx1 = sx - x0f, wx0 = 1.f - wx1;
    bool vy0 = (y0f >= 0.f) && (y0f <= 127.f);
    bool vy1 = (y0f >= -1.f) && (y0f <= 126.f);
    bool vx0 = (x0f >= 0.f) && (x0f <= 127.f);
    bool vx1 = (x0f >= -1.f) && (x0f <= 126.f);
    int yi0 = (int)fminf(fmaxf(y0f, 0.f), 127.f);
    int yi1 = (int)fminf(fmaxf(y0f + 1.f, 0.f), 127.f);
    int xi0 = (int)fminf(fmaxf(x0f, 0.f), 127.f);
    int xi1 = (int)fminf(fmaxf(x0f + 1.f, 0.f), 127.f);
    float w00 = wy0 * wx0 * ((vy0 && vx0) ? 1.f : 0.f);
    float w01 = wy0 * wx1 * ((vy0 && vx1) ? 1.f : 0.f);
    float w10 = wy1 * wx0 * ((vy1 && vx0) ? 1.f : 0.f);
    float w11 = wy1 * wx1 * ((vy1 && vx1) ? 1.f : 0.f);

    const __bf16* c00 = xb + ((size_t)((yi0 + 3) * 134) + xi0 + 3) * 64 + og * 32;
    const __bf16* c01 = xb + ((size_t)((yi0 + 3) * 134) + xi1 + 3) * 64 + og * 32;
    const __bf16* c10 = xb + ((size_t)((yi1 + 3) * 134) + xi0 + 3) * 64 + og * 32;
    const __bf16* c11 = xb + ((size_t)((yi1 + 3) * 134) + xi1 + 3) * 64 + og * 32;

#pragma unroll
    for (int o4 = 0; o4 < 4; o4++) {
      bf16x8 v00 = *(const bf16x8*)(c00 + o4 * 8);
      bf16x8 v01 = *(const bf16x8*)(c01 + o4 * 8);
      bf16x8 v10 = *(const bf16x8*)(c10 + o4 * 8);
      bf16x8 v11 = *(const bf16x8*)(c11 + o4 * 8);
      bf16x8 r;
#pragma unroll
      for (int j = 0; j < 8; j++) {
        float f = w00 * (float)v00[j] + w01 * (float)v01[j]
                + w10 * (float)v10[j] + w11 * (float)v11[j];
        r[j] = (__bf16)f;
      }
      // octet row = og*4+o4; 32px x 16B = 512B per octet row
      *(bf16x8*)(sm + (og * 4 + o4) * 512 + p * 16) = r;
    }

#pragma unroll
    for (int s = 0; s < 2; s++) {
      bf16x8 a0 = aD[((k * 2 + s) * 4 + 0) * 64 + lane];
      bf16x8 a1 = aD[((k * 2 + s) * 4 + 1) * 64 + lane];
      bf16x8 a2 = aD[((k * 2 + s) * 4 + 2) * 64 + lane];
      bf16x8 a3 = aD[((k * 2 + s) * 4 + 3) * 64 + lane];
#pragma unroll
      for (int nf = 0; nf < 2; nf++) {
        bf16x8 bv = *(const bf16x8*)(sm + (s * 4 + (lane >> 4)) * 512
                                        + (nf * 16 + (lane & 15)) * 16);
        acc[0][nf] = __builtin_amdgcn_mfma_f32_16x16x32_bf16(a0, bv, acc[0][nf], 0, 0, 0);
        acc[1][nf] = __builtin_amdgcn_mfma_f32_16x16x32_bf16(a1, bv, acc[1][nf], 0, 0, 0);
        acc[2][nf] = __builtin_amdgcn_mfma_f32_16x16x32_bf16(a2, bv, acc[2][nf], 0, 0, 0);
        acc[3][nf] = __builtin_amdgcn_mfma_f32_16x16x32_bf16(a3, bv, acc[3][nf], 0, 0, 0);
      }
    }
  }

#pragma unroll
  for (int mf = 0; mf < 4; mf++) {
    int o = mf * 16 + ((lane >> 4) << 2);
    float b0 = dcn_b[o], b1v = dcn_b[o + 1], b2v = dcn_b[o + 2], b3v = dcn_b[o + 3];
#pragma unroll
    for (int nf = 0; nf < 2; nf++) {
      int px = q * 32 + nf * 16 + (lane & 15);
      bf16x4 r;
      r[0] = (__bf16)(acc[mf][nf][0] + b0);
      r[1] = (__bf16)(acc[mf][nf][1] + b1v);
      r[2] = (__bf16)(acc[mf][nf][2] + b2v);
      r[3] = (__bf16)(acc[mf][nf][3] + b3v);
      *(bf16x4*)(FdT + ((size_t)b * HWn + h * 128 + px) * 64 + o) = r;
    }
  }
}

// ---------------------------------------------------------------------------
// K7: fusion -> fusedT bf16 channels-last, zero-padded 2 ring [b][132][132][64].
// ---------------------------------------------------------------------------
__global__ __launch_bounds__(256) void k_fuseT(
    const __bf16* __restrict__ FsT, const __bf16* __restrict__ FdT,
    const float* __restrict__ wg_w, const float* __restrict__ wg_b,
    __bf16* __restrict__ fusedT)
{
  int id = blockIdx.x * 256 + threadIdx.x;
  if (id >= 8 * 132 * 132) return;
  int wp = id % 132;
  int hp = (id / 132) % 132;
  int b  = id / (132 * 132);
  __bf16* dst = fusedT + (size_t)id * 64;
  int h = hp - 2, w = wp - 2;
  if (((unsigned)h >= 128u) || ((unsigned)w >= 128u)) {
    bf16x8 z = {};
#pragma unroll
    for (int oct = 0; oct < 8; oct++) *(bf16x8*)(dst + oct * 8) = z;
    return;
  }
  const bf16x8* fs = (const bf16x8*)(FsT + ((size_t)b * HWn + h * 128 + w) * 64);
  const bf16x8* fd = (const bf16x8*)(FdT + ((size_t)b * HWn + h * 128 + w) * 64);
  bf16x8 fsv[8], fdv[8];
  float s0 = wg_b[0], s1 = wg_b[1];
#pragma unroll
  for (int oct = 0; oct < 8; oct++) {
    fsv[oct] = fs[oct];
    fdv[oct] = fd[oct];
#pragma unroll
    for (int j = 0; j < 8; j++) {
      int c = oct * 8 + j;
      float a = (float)fsv[oct][j], d = (float)fdv[oct][j];
      s0 = fmaf(wg_w[c],       a, fmaf(wg_w[64 + c],  d, s0));
      s1 = fmaf(wg_w[128 + c], a, fmaf(wg_w[192 + c], d, s1));
    }
  }
  float p0 = 1.f / (1.f + __expf(s1 - s0));
  float p1 = 1.f - p0;
#pragma unroll
  for (int oct = 0; oct < 8; oct++) {
    bf16x8 r;
#pragma unroll
    for (int j = 0; j < 8; j++)
      r[j] = (__bf16)(p0 * (float)fsv[oct][j] + p1 * (float)fdv[oct][j]);
    *(bf16x8*)(dst + oct * 8) = r;
  }
}

// ---------------------------------------------------------------------------
// K8: collapsed ELK via MFMA. XCD swizzle chunk 64 => XCD k = batch k.
// ---------------------------------------------------------------------------
__global__ __launch_bounds__(256) void k_elkm(
    const __bf16* __restrict__ fusedT, const __bf16* __restrict__ weffD,
    const float* __restrict__ beff, float* __restrict__ out)
{
  const int DY[13] = {-2,-1,-1,-1, 0, 0, 0, 0, 0, 1, 1, 1, 2};
  const int DX[13] = { 0,-1, 0, 1,-2,-1, 0, 1, 2,-1, 0, 1, 0};
  const int lane = threadIdx.x & 63;
  const int wv   = threadIdx.x >> 6;
  const int swz  = xcd_swz(blockIdx.x, 64);
  const int b    = swz >> 6;
  const int h    = (swz & 63) * 2 + (wv >> 1);
  const int half = wv & 1;

  f32x4 acc[4][4];
#pragma unroll
  for (int mf = 0; mf < 4; mf++)
#pragma unroll
    for (int nf = 0; nf < 4; nf++) acc[mf][nf] = (f32x4){0.f, 0.f, 0.f, 0.f};

  const bf16x8* aD = (const bf16x8*)weffD;

  for (int t = 0; t < 13; t++) {
    int hp = h + 2 + DY[t];
    const __bf16* base = fusedT
        + ((size_t)((b * 132 + hp) * 132) + half * 64 + 2 + DX[t]) * 64;
#pragma unroll
    for (int s = 0; s < 2; s++) {
      bf16x8 a0 = aD[((t * 2 + s) * 4 + 0) * 64 + lane];
      bf16x8 a1 = aD[((t * 2 + s) * 4 + 1) * 64 + lane];
      bf16x8 a2 = aD[((t * 2 + s) * 4 + 2) * 64 + lane];
      bf16x8 a3 = aD[((t * 2 + s) * 4 + 3) * 64 + lane];
#pragma unroll
      for (int nf = 0; nf < 4; nf++) {
        bf16x8 bv = *(const bf16x8*)(base + (size_t)(nf * 16 + (lane & 15)) * 64
                                          + s * 32 + (lane >> 4) * 8);
        acc[0][nf] = __builtin_amdgcn_mfma_f32_16x16x32_bf16(a0, bv, acc[0][nf], 0, 0, 0);
        acc[1][nf] = __builtin_amdgcn_mfma_f32_16x16x32_bf16(a1, bv, acc[1][nf], 0, 0, 0);
        acc[2][nf] = __builtin_amdgcn_mfma_f32_16x16x32_bf16(a2, bv, acc[2][nf], 0, 0, 0);
        acc[3][nf] = __builtin_amdgcn_mfma_f32_16x16x32_bf16(a3, bv, acc[3][nf], 0, 0, 0);
      }
    }
  }

#pragma unroll
  for (int mf = 0; mf < 4; mf++) {
    int ob = mf * 16 + ((lane >> 4) << 2);
#pragma unroll
    for (int r = 0; r < 4; r++) {
      int o = ob + r;
      float bb = beff[o];
      float* orow = out + ((size_t)(b * 64 + o)) * HWn + h * 128 + half * 64 + (lane & 15);
#pragma unroll
      for (int nf = 0; nf < 4; nf++)
        orow[nf * 16] = acc[mf][nf][r] + bb;
    }
  }
}

// ---------------------------------------------------------------------------
// Workspace layout unchanged from R5 (all sizes verified in floats):
// Region A [0, 4,596,736): xT -> fusedT (after k_dcnm).
// Region B [4,596,736, 9,536,512): xC -> FsT (after k_conv1m).
// Region C [9,536,512, 14,322,688): t1T/p1T/t2 -> FdT (after k_feat).
// Tail: feat/theta/wfrag/w2frag/beff/dcnD/weffD @14,322,688.. end 14,444,160.
// ---------------------------------------------------------------------------
extern "C" void kernel_launch(void* const* d_in, const int* in_sizes, int n_in,
                              void* d_out, int out_size, void* d_ws, size_t ws_size,
                              hipStream_t stream)
{
  (void)in_sizes; (void)n_in; (void)out_size; (void)ws_size;
  const float* x      = (const float*)d_in[0];
  const float* offset = (const float*)d_in[1];
  const float* stn_w1 = (const float*)d_in[2];
  const float* stn_b1 = (const float*)d_in[3];
  const float* stn_w2 = (const float*)d_in[4];
  const float* stn_b2 = (const float*)d_in[5];
  const float* fc_w   = (const float*)d_in[6];
  const float* fc_b   = (const float*)d_in[7];
  const float* dcn_w  = (const float*)d_in[8];
  const float* dcn_b  = (const float*)d_in[9];
  const float* wg_w   = (const float*)d_in[10];
  const float* wg_b   = (const float*)d_in[11];
  const float* w3     = (const float*)d_in[12];
  const float* b3     = (const float*)d_in[13];
  const float* w15    = (const float*)d_in[14];
  const float* b15    = (const float*)d_in[15];
  const float* w51    = (const float*)d_in[16];
  const float* b51    = (const float*)d_in[17];
  const float* w1     = (const float*)d_in[18];
  const float* b1     = (const float*)d_in[19];

  float* ws      = (float*)d_ws;
  __bf16* xT     = (__bf16*)ws;
  __bf16* fusedT = (__bf16*)ws;
  __bf16* xC     = (__bf16*)(ws + 4596736);
  __bf16* FsT    = (__bf16*)(ws + 4596736);
  __bf16* t1T    = (__bf16*)(ws + 9536512);
  __bf16* FdT    = (__bf16*)(ws + 9536512);
  __bf16* p1T    = (__bf16*)(ws + 11633664);
  float*  t2     = ws + 12225536;
  float*  feat   = ws + 14322688;
  float*  theta  = ws + 14323200;
  __bf16* wfrag  = (__bf16*)(ws + 14323264);
  __bf16* w2frag = (__bf16*)(ws + 14373440);
  float*  beff   = ws + 14399040;
  __bf16* dcnD   = (__bf16*)(ws + 14399104);
  __bf16* weffD  = (__bf16*)(ws + 14417536);
  float*  out    = (float*)d_out;

  k_prep  <<<1,    64,  0, stream>>>(w1, b3, b15, b51, b1, beff);
  k_xt    <<<562,  256, 0, stream>>>(x, xT, xC);
  k_wf    <<<392,  256, 0, stream>>>(stn_w1, wfrag);
  k_frag  <<<552,  256, 0, stream>>>(dcn_w, w1, w3, w15, w51, stn_w2, dcnD, weffD, w2frag);
  k_conv1m<<<512,  128, 0, stream>>>(xC, wfrag, stn_b1, t1T);
  k_pool  <<<145,  256, 0, stream>>>(t1T, p1T);
  k_conv2m<<<128,  256, 0, stream>>>(p1T, w2frag, stn_b2, t2);
  k_feat  <<<512,  256, 0, stream>>>(t2, feat);
  k_theta <<<1,    64,  0, stream>>>(feat, fc_w, fc_b, theta);
  k_fs    <<<512,  256, 0, stream>>>(xT, theta, FsT);
  k_dcnm  <<<1024, 256, 0, stream>>>(xT, offset, dcnD, dcn_b, FdT);
  k_fuseT <<<545,  256, 0, stream>>>(FsT, FdT, wg_w, wg_b, fusedT);
  k_elkm  <<<512,  256, 0, stream>>>(fusedT, weffD, beff, out);
}